// Round 3
// baseline (1228.980 us; speedup 1.0000x reference)
//
#include <hip/hip_runtime.h>
#include <hip/hip_bf16.h>

#define E 256
#define H 16
#define DD 16
#define FFH 512
#define LAYERS 5
#define BB 4
#define NN 256
#define MROWS 1024  // B*N

// ---------------- prep kernels ----------------

__global__ void k_minmax(const float* __restrict__ data, float* __restrict__ stats) {
    int b = blockIdx.x;
    const float* p = data + (size_t)b * NN * NN;
    float lmin = 1e30f, lmax = -1e30f;
    for (int i = threadIdx.x; i < NN * NN; i += 256) {
        float v = p[i];
        lmin = fminf(lmin, v);
        lmax = fmaxf(lmax, v);
    }
    #pragma unroll
    for (int off = 32; off; off >>= 1) {
        lmin = fminf(lmin, __shfl_down(lmin, off));
        lmax = fmaxf(lmax, __shfl_down(lmax, off));
    }
    __shared__ float smin[4], smax[4];
    int wid = threadIdx.x >> 6, lane = threadIdx.x & 63;
    if (lane == 0) { smin[wid] = lmin; smax[wid] = lmax; }
    __syncthreads();
    if (threadIdx.x == 0) {
        float mn = fminf(fminf(smin[0], smin[1]), fminf(smin[2], smin[3]));
        float mx = fmaxf(fmaxf(smax[0], smax[1]), fmaxf(smax[2], smax[3]));
        float rng = mx - mn;
        if (rng == 0.f) rng = 1.f;
        stats[b] = mn;
        stats[4 + b] = 1.f / rng;
    }
}

// c1[lj,h] = sum_e Wedge[e]*Wmix[lj,e,h];  c0[lj,h] = sum_e bedge[e]*Wmix[lj,e,h]
__global__ void k_mix(const float* __restrict__ Wedge, const float* __restrict__ bedge,
                      const float* __restrict__ Wmix, float* __restrict__ c1c0) {
    int p = threadIdx.x;
    if (p < LAYERS * 2 * H) {
        int lj = p >> 4, h = p & 15;
        float c1 = 0.f, c0 = 0.f;
        for (int e = 0; e < E; e++) {
            float wm = Wmix[(lj * E + e) * H + h];
            c1 += Wedge[e] * wm;
            c0 += bedge[e] * wm;
        }
        c1c0[p] = c1;
        c1c0[160 + p] = c0;
    }
}

__global__ void k_scale(const float* __restrict__ data, const float* __restrict__ stats,
                        float* __restrict__ sc, float* __restrict__ scT) {
    int idx = blockIdx.x * 256 + threadIdx.x;
    int b = idx >> 16;
    int rem = idx & 65535;
    int n = rem >> 8, m = rem & 255;
    float v = (data[idx] - stats[b]) * stats[4 + b];
    sc[idx] = v;
    scT[(b << 16) + (m << 8) + n] = v;
}

__global__ void k_emb(const float* __restrict__ node_rand, const float* __restrict__ Wnode,
                      const float* __restrict__ bnode, float* __restrict__ rowb,
                      float* __restrict__ colb) {
    int idx = blockIdx.x * 256 + threadIdx.x;
    int bn = idx >> 8, e = idx & 255;
    float v = node_rand[bn] * Wnode[e] + bnode[e];
    rowb[idx] = v;
    colb[idx] = v;
}

// ---------------- generic fp32 GEMM (A [1024,K], W [K,Ncols]) ----------------
// block: 256 threads, 64x64 tile; grid.x = 1024/64 = 16, grid.y = Ncols/64

__device__ __forceinline__ void gemm_dev(const float* __restrict__ A, const float* __restrict__ W,
                                         const float* __restrict__ bias, const float* __restrict__ R,
                                         float* __restrict__ C, int K, int Ncols, int relu) {
    __shared__ float As[16][68];  // [k][m]
    __shared__ float Ws[16][68];  // [k][n]
    int tid = threadIdx.x;
    int tx = tid & 15, ty = tid >> 4;
    int mBase = blockIdx.x * 64, nBase = blockIdx.y * 64;
    float acc[4][4] = {};
    for (int kt = 0; kt < K; kt += 16) {
        #pragma unroll
        for (int i = 0; i < 4; i++) {
            int lin = tid + i * 256;
            int m = lin >> 4, kk = lin & 15;
            As[kk][m] = A[(size_t)(mBase + m) * K + kt + kk];
        }
        #pragma unroll
        for (int i = 0; i < 4; i++) {
            int lin = tid + i * 256;
            int kk = lin >> 6, n = lin & 63;
            Ws[kk][n] = W[(size_t)(kt + kk) * Ncols + nBase + n];
        }
        __syncthreads();
        #pragma unroll
        for (int kk = 0; kk < 16; kk++) {
            float4 a4 = *(const float4*)&As[kk][ty * 4];
            float4 b4 = *(const float4*)&Ws[kk][tx * 4];
            float av[4] = {a4.x, a4.y, a4.z, a4.w};
            float bw[4] = {b4.x, b4.y, b4.z, b4.w};
            #pragma unroll
            for (int i = 0; i < 4; i++)
                #pragma unroll
                for (int j = 0; j < 4; j++) acc[i][j] += av[i] * bw[j];
        }
        __syncthreads();
    }
    #pragma unroll
    for (int i = 0; i < 4; i++) {
        int r = mBase + ty * 4 + i;
        #pragma unroll
        for (int j = 0; j < 4; j++) {
            int c = nBase + tx * 4 + j;
            float v = acc[i][j];
            if (bias) v += bias[c];
            if (R) v += R[(size_t)r * Ncols + c];
            if (relu) v = fmaxf(v, 0.f);
            C[(size_t)r * Ncols + c] = v;
        }
    }
}

// z = j*3 + which(q/k/v)
__global__ __launch_bounds__(256) void k_qkv(const float* __restrict__ row, const float* __restrict__ col,
                                             const float* __restrict__ Wq_l, const float* __restrict__ Wk_l,
                                             const float* __restrict__ Wv_l,
                                             float* q0, float* k0, float* v0,
                                             float* q1, float* k1, float* v1) {
    int z = blockIdx.z;
    int j = z / 3, w = z % 3;
    const float* A = (w == 0) ? (j == 0 ? row : col) : (j == 0 ? col : row);
    const float* W = (w == 0 ? Wq_l : (w == 1 ? Wk_l : Wv_l)) + (size_t)j * E * E;
    float* outs[6] = {q0, k0, v0, q1, k1, v1};
    gemm_dev(A, W, nullptr, nullptr, outs[z], E, E, 0);
}

__global__ __launch_bounds__(256) void k_gemm2(const float* __restrict__ A0, const float* __restrict__ A1,
                                               const float* __restrict__ Wl, int wstride,
                                               const float* __restrict__ biasl, int bstride,
                                               const float* __restrict__ R0, const float* __restrict__ R1,
                                               float* O0, float* O1, int K, int Ncols, int relu) {
    int j = blockIdx.z;
    gemm_dev(j ? A1 : A0, Wl + (size_t)j * wstride, biasl ? biasl + (size_t)j * bstride : nullptr,
             (R0 == nullptr) ? nullptr : (j ? R1 : R0), j ? O1 : O0, K, Ncols, relu);
}

// ---------------- fused attention ----------------
// grid: (B*H, 2 n-chunks, 2 j), block 128 threads (one row n each)
__global__ __launch_bounds__(128) void k_attn(const float* __restrict__ q0, const float* __restrict__ k0,
                                              const float* __restrict__ v0, const float* __restrict__ q1,
                                              const float* __restrict__ k1, const float* __restrict__ v1,
                                              const float* __restrict__ sc, const float* __restrict__ scT,
                                              const float* __restrict__ c1c0, int lj_base,
                                              float* __restrict__ att0, float* __restrict__ att1) {
    int bh = blockIdx.x;
    int b = bh >> 4, h = bh & 15;
    int nc = blockIdx.y;
    int j = blockIdx.z;
    const float* q = j ? q1 : q0;
    const float* k = j ? k1 : k0;
    const float* v = j ? v1 : v0;
    const float* scm = (j ? scT : sc) + (size_t)b * NN * NN;
    float c1 = c1c0[(lj_base + j) * 16 + h];
    float c0 = c1c0[160 + (lj_base + j) * 16 + h];

    __shared__ float kl[256][20];
    __shared__ float vl[256][20];
    int t = threadIdx.x;
    for (int m = t; m < 256; m += 128) {
        const float* kp = k + ((size_t)(b * NN + m) * E) + h * DD;
        const float* vp = v + ((size_t)(b * NN + m) * E) + h * DD;
        #pragma unroll
        for (int d4 = 0; d4 < 4; d4++) {
            *(float4*)&kl[m][d4 * 4] = *(const float4*)(kp + d4 * 4);
            *(float4*)&vl[m][d4 * 4] = *(const float4*)(vp + d4 * 4);
        }
    }
    __syncthreads();

    int n = nc * 128 + t;
    float qr[16];
    const float* qp = q + ((size_t)(b * NN + n) * E) + h * DD;
    #pragma unroll
    for (int d4 = 0; d4 < 4; d4++) {
        float4 q4 = *(const float4*)(qp + d4 * 4);
        qr[d4 * 4 + 0] = q4.x; qr[d4 * 4 + 1] = q4.y; qr[d4 * 4 + 2] = q4.z; qr[d4 * 4 + 3] = q4.w;
    }
    const float* srow = scm + (size_t)n * NN;

    float mrun = -INFINITY, sum = 0.f;
    float acc[16] = {};
    for (int m = 0; m < 256; m++) {
        float s = 0.f;
        #pragma unroll
        for (int d = 0; d < 16; d++) s += qr[d] * kl[m][d];
        s = s * 0.25f + srow[m] * c1 + c0;
        if (s > mrun) {
            float r = __expf(mrun - s);
            sum *= r;
            #pragma unroll
            for (int d = 0; d < 16; d++) acc[d] *= r;
            mrun = s;
        }
        float e = __expf(s - mrun);
        sum += e;
        #pragma unroll
        for (int d = 0; d < 16; d++) acc[d] += e * vl[m][d];
    }
    float inv = 1.f / sum;
    float* op = (j ? att1 : att0) + ((size_t)(b * NN + n) * E) + h * DD;
    #pragma unroll
    for (int d = 0; d < 16; d++) op[d] = acc[d] * inv;
}

// ---------------- instance norm over node dim ----------------
// grid: (B, 2 j), block 1024 (4 n-slices x 256 channels)
__global__ __launch_bounds__(1024) void k_inorm(const float* __restrict__ Y0, const float* __restrict__ Y1,
                                                const float* __restrict__ wl, const float* __restrict__ bl,
                                                int pstride, float* __restrict__ O0, float* __restrict__ O1,
                                                float* __restrict__ fout) {
    int b = blockIdx.x, j = blockIdx.y;
    const float* Y = (j ? Y1 : Y0) + (size_t)b * NN * E;
    float* O = (j ? O1 : O0) + (size_t)b * NN * E;
    const float* w = wl + (size_t)j * pstride;
    const float* bbp = bl + (size_t)j * pstride;
    int t = threadIdx.x;
    int e = t & 255, n0 = t >> 8;
    float s = 0.f, s2 = 0.f;
    for (int n = n0; n < NN; n += 4) {
        float v = Y[(size_t)n * E + e];
        s += v;
        s2 += v * v;
    }
    __shared__ float ps[4][256], ps2[4][256];
    ps[n0][e] = s;
    ps2[n0][e] = s2;
    __syncthreads();
    float st = ps[0][e] + ps[1][e] + ps[2][e] + ps[3][e];
    float st2 = ps2[0][e] + ps2[1][e] + ps2[2][e] + ps2[3][e];
    float mu = st * (1.f / NN);
    float var = st2 * (1.f / NN) - mu * mu;
    var = fmaxf(var, 0.f);
    float scale = w[e] * rsqrtf(var + 1e-5f);
    float shift = bbp[e] - mu * scale;
    for (int n = n0; n < NN; n += 4) {
        float v = Y[(size_t)n * E + e] * scale + shift;
        O[(size_t)n * E + e] = v;
        if (fout) fout[(size_t)j * (BB * NN * E) + (size_t)b * NN * E + (size_t)n * E + e] = v;
    }
}

// ---------------- host ----------------
// Workspace layout (T = 262144 floats = 1 MB each), total 12 T + ~1.3 KB:
//   0: sc   1: scT   2: row   3: col
//   4: q0 / y0 / y20     5: q1 / y1 / y21
//   6: k0 / o10          7: k1 / o11
//   8-9:  v0,v1  -> ffh0 (2T contiguous; v dead after attn)
//   10-11: att0,att1 -> ffh1 (2T contiguous; att dead after comb)
//   12: stats(8) + c1c0(320)
// Liveness verified per stage: no region is read after being reused.

extern "C" void kernel_launch(void* const* d_in, const int* in_sizes, int n_in,
                              void* d_out, int out_size, void* d_ws, size_t ws_size,
                              hipStream_t stream) {
    const float* data      = (const float*)d_in[0];
    const float* node_rand = (const float*)d_in[1];
    const float* Wnode     = (const float*)d_in[2];
    const float* bnode     = (const float*)d_in[3];
    const float* Wedge     = (const float*)d_in[4];
    const float* bedge     = (const float*)d_in[5];
    const float* Wq        = (const float*)d_in[6];
    const float* Wk        = (const float*)d_in[7];
    const float* Wv        = (const float*)d_in[8];
    const float* Wcomb     = (const float*)d_in[9];
    const float* bcomb     = (const float*)d_in[10];
    const float* n1w       = (const float*)d_in[11];
    const float* n1b       = (const float*)d_in[12];
    const float* W1        = (const float*)d_in[13];
    const float* b1        = (const float*)d_in[14];
    const float* W2        = (const float*)d_in[15];
    const float* b2        = (const float*)d_in[16];
    const float* n2w       = (const float*)d_in[17];
    const float* n2b       = (const float*)d_in[18];
    const float* Wmix      = (const float*)d_in[19];
    float* out = (float*)d_out;  // (row, col) concat: row @ 0, col @ B*N*E

    float* ws = (float*)d_ws;
    const size_t T = (size_t)MROWS * E;  // 262144 floats
    float* sc   = ws + 0 * T;
    float* scT  = ws + 1 * T;
    float* row  = ws + 2 * T;
    float* col  = ws + 3 * T;
    float* q0   = ws + 4 * T;
    float* q1   = ws + 5 * T;
    float* k0   = ws + 6 * T;
    float* k1   = ws + 7 * T;
    float* v0   = ws + 8 * T;
    float* v1   = ws + 9 * T;
    float* att0 = ws + 10 * T;
    float* att1 = ws + 11 * T;
    float* stats = ws + 12 * T;
    float* c1c0  = ws + 12 * T + 8;
    // aliases (liveness-checked)
    float* y0  = q0;  float* y1  = q1;    // comb out (q dead after attn)
    float* o10 = k0;  float* o11 = k1;    // IN1 out (k dead after attn)
    float* ffh0 = v0;                      // 2T: v0+v1 (v dead after attn)
    float* ffh1 = att0;                    // 2T: att0+att1 (att dead after comb)
    float* y20 = q0;  float* y21 = q1;    // FF2 out (y dead after IN1)

    k_minmax<<<BB, 256, 0, stream>>>(data, stats);
    k_mix<<<1, 256, 0, stream>>>(Wedge, bedge, Wmix, c1c0);
    k_scale<<<(BB * NN * NN) / 256, 256, 0, stream>>>(data, stats, sc, scT);
    k_emb<<<(BB * NN * E) / 256, 256, 0, stream>>>(node_rand, Wnode, bnode, row, col);

    for (int l = 0; l < LAYERS; l++) {
        const float* Wq_l = Wq + (size_t)l * 2 * E * E;
        const float* Wk_l = Wk + (size_t)l * 2 * E * E;
        const float* Wv_l = Wv + (size_t)l * 2 * E * E;

        k_qkv<<<dim3(16, 4, 6), 256, 0, stream>>>(row, col, Wq_l, Wk_l, Wv_l,
                                                  q0, k0, v0, q1, k1, v1);
        k_attn<<<dim3(64, 2, 2), 128, 0, stream>>>(q0, k0, v0, q1, k1, v1, sc, scT,
                                                   c1c0, l * 2, att0, att1);
        k_gemm2<<<dim3(16, 4, 2), 256, 0, stream>>>(att0, att1, Wcomb + (size_t)l * 2 * E * E, E * E,
                                                    bcomb + (size_t)l * 2 * E, E, row, col,
                                                    y0, y1, E, E, 0);
        k_inorm<<<dim3(BB, 2), 1024, 0, stream>>>(y0, y1, n1w + (size_t)l * 2 * E, n1b + (size_t)l * 2 * E,
                                                  E, o10, o11, nullptr);
        k_gemm2<<<dim3(16, 8, 2), 256, 0, stream>>>(o10, o11, W1 + (size_t)l * 2 * E * FFH, E * FFH,
                                                    b1 + (size_t)l * 2 * FFH, FFH, nullptr, nullptr,
                                                    ffh0, ffh1, E, FFH, 1);
        k_gemm2<<<dim3(16, 4, 2), 256, 0, stream>>>(ffh0, ffh1, W2 + (size_t)l * 2 * FFH * E, FFH * E,
                                                    b2 + (size_t)l * 2 * E, E, o10, o11,
                                                    q0 /*y20*/, q1 /*y21*/, FFH, E, 0);
        k_inorm<<<dim3(BB, 2), 1024, 0, stream>>>(y20, y21, n2w + (size_t)l * 2 * E, n2b + (size_t)l * 2 * E,
                                                  E, row, col, (l == LAYERS - 1) ? out : nullptr);
    }
}

// Round 4
// 1102.830 us; speedup vs baseline: 1.1144x; 1.1144x over previous
//
#include <hip/hip_runtime.h>
#include <hip/hip_bf16.h>

#define E 256
#define H 16
#define DD 16
#define FFH 512
#define LAYERS 5
#define BB 4
#define NN 256
#define MROWS 1024  // B*N

// ---------------- prep: two-stage min/max ----------------
// stage 1: grid (BB,16), 256 thr; each block reduces 4096 elems -> pmin/pmax[b*16+p]
__global__ void k_minmax1(const float* __restrict__ data, float* __restrict__ pmin,
                          float* __restrict__ pmax) {
    int b = blockIdx.x, p = blockIdx.y;
    const float* src = data + (size_t)b * NN * NN + p * 4096;
    float lmin = 1e30f, lmax = -1e30f;
    #pragma unroll
    for (int i = 0; i < 16; i++) {
        float v = src[threadIdx.x + i * 256];
        lmin = fminf(lmin, v);
        lmax = fmaxf(lmax, v);
    }
    #pragma unroll
    for (int off = 32; off; off >>= 1) {
        lmin = fminf(lmin, __shfl_down(lmin, off));
        lmax = fmaxf(lmax, __shfl_down(lmax, off));
    }
    __shared__ float smin[4], smax[4];
    int wid = threadIdx.x >> 6, lane = threadIdx.x & 63;
    if (lane == 0) { smin[wid] = lmin; smax[wid] = lmax; }
    __syncthreads();
    if (threadIdx.x == 0) {
        pmin[b * 16 + p] = fminf(fminf(smin[0], smin[1]), fminf(smin[2], smin[3]));
        pmax[b * 16 + p] = fmaxf(fmaxf(smax[0], smax[1]), fmaxf(smax[2], smax[3]));
    }
}

// stage 2 (1 block, 256 thr): t<4 -> finalize stats[b]; t in [64,224) -> mix constants
// c1[lj,h] = sum_e Wedge[e]*Wmix[lj,e,h];  c0[lj,h] = sum_e bedge[e]*Wmix[lj,e,h]
__global__ void k_final(const float* __restrict__ pmin, const float* __restrict__ pmax,
                        const float* __restrict__ Wedge, const float* __restrict__ bedge,
                        const float* __restrict__ Wmix, float* __restrict__ stats,
                        float* __restrict__ c1c0) {
    int t = threadIdx.x;
    if (t < 4) {
        float mn = 1e30f, mx = -1e30f;
        #pragma unroll
        for (int p = 0; p < 16; p++) {
            mn = fminf(mn, pmin[t * 16 + p]);
            mx = fmaxf(mx, pmax[t * 16 + p]);
        }
        float rng = mx - mn;
        if (rng == 0.f) rng = 1.f;
        stats[t] = mn;
        stats[4 + t] = 1.f / rng;
    } else if (t >= 64 && t < 64 + LAYERS * 2 * H) {
        int p = t - 64;
        int lj = p >> 4, h = p & 15;
        float c1 = 0.f, c0 = 0.f;
        for (int e = 0; e < E; e++) {
            float wm = Wmix[(lj * E + e) * H + h];
            c1 += Wedge[e] * wm;
            c0 += bedge[e] * wm;
        }
        c1c0[p] = c1;
        c1c0[160 + p] = c0;
    }
}

__global__ void k_emb(const float* __restrict__ node_rand, const float* __restrict__ Wnode,
                      const float* __restrict__ bnode, float* __restrict__ rowb,
                      float* __restrict__ colb) {
    int idx = blockIdx.x * 256 + threadIdx.x;
    int bn = idx >> 8, e = idx & 255;
    float v = node_rand[bn] * Wnode[e] + bnode[e];
    rowb[idx] = v;
    colb[idx] = v;
}

// ---------------- generic fp32 GEMM (A [1024,K], W [K,Ncols]) ----------------
// block: 256 threads, 64x64 tile; grid.x = 1024/64 = 16, grid.y = Ncols/64

__device__ __forceinline__ void gemm_dev(const float* __restrict__ A, const float* __restrict__ W,
                                         const float* __restrict__ bias, const float* __restrict__ R,
                                         float* __restrict__ C, int K, int Ncols, int relu) {
    __shared__ float As[16][68];  // [k][m]
    __shared__ float Ws[16][68];  // [k][n]
    int tid = threadIdx.x;
    int tx = tid & 15, ty = tid >> 4;
    int mBase = blockIdx.x * 64, nBase = blockIdx.y * 64;
    float acc[4][4] = {};
    for (int kt = 0; kt < K; kt += 16) {
        #pragma unroll
        for (int i = 0; i < 4; i++) {
            int lin = tid + i * 256;
            int m = lin >> 4, kk = lin & 15;
            As[kk][m] = A[(size_t)(mBase + m) * K + kt + kk];
        }
        #pragma unroll
        for (int i = 0; i < 4; i++) {
            int lin = tid + i * 256;
            int kk = lin >> 6, n = lin & 63;
            Ws[kk][n] = W[(size_t)(kt + kk) * Ncols + nBase + n];
        }
        __syncthreads();
        #pragma unroll
        for (int kk = 0; kk < 16; kk++) {
            float4 a4 = *(const float4*)&As[kk][ty * 4];
            float4 b4 = *(const float4*)&Ws[kk][tx * 4];
            float av[4] = {a4.x, a4.y, a4.z, a4.w};
            float bw[4] = {b4.x, b4.y, b4.z, b4.w};
            #pragma unroll
            for (int i = 0; i < 4; i++)
                #pragma unroll
                for (int j = 0; j < 4; j++) acc[i][j] += av[i] * bw[j];
        }
        __syncthreads();
    }
    #pragma unroll
    for (int i = 0; i < 4; i++) {
        int r = mBase + ty * 4 + i;
        #pragma unroll
        for (int j = 0; j < 4; j++) {
            int c = nBase + tx * 4 + j;
            float v = acc[i][j];
            if (bias) v += bias[c];
            if (R) v += R[(size_t)r * Ncols + c];
            if (relu) v = fmaxf(v, 0.f);
            C[(size_t)r * Ncols + c] = v;
        }
    }
}

// z = j*3 + which(q/k/v)
__global__ __launch_bounds__(256) void k_qkv(const float* __restrict__ row, const float* __restrict__ col,
                                             const float* __restrict__ Wq_l, const float* __restrict__ Wk_l,
                                             const float* __restrict__ Wv_l,
                                             float* q0, float* k0, float* v0,
                                             float* q1, float* k1, float* v1) {
    int z = blockIdx.z;
    int j = z / 3, w = z % 3;
    const float* A = (w == 0) ? (j == 0 ? row : col) : (j == 0 ? col : row);
    const float* W = (w == 0 ? Wq_l : (w == 1 ? Wk_l : Wv_l)) + (size_t)j * E * E;
    float* outs[6] = {q0, k0, v0, q1, k1, v1};
    gemm_dev(A, W, nullptr, nullptr, outs[z], E, E, 0);
}

__global__ __launch_bounds__(256) void k_gemm2(const float* __restrict__ A0, const float* __restrict__ A1,
                                               const float* __restrict__ Wl, int wstride,
                                               const float* __restrict__ biasl, int bstride,
                                               const float* __restrict__ R0, const float* __restrict__ R1,
                                               float* O0, float* O1, int K, int Ncols, int relu) {
    int j = blockIdx.z;
    gemm_dev(j ? A1 : A0, Wl + (size_t)j * wstride, biasl ? biasl + (size_t)j * bstride : nullptr,
             (R0 == nullptr) ? nullptr : (j ? R1 : R0), j ? O1 : O0, K, Ncols, relu);
}

// ---------------- fused attention ----------------
// grid: (B*H, 2 n-chunks, 2 j), block 128 threads (one row n each)
// edge bias read straight from `data` with per-batch affine fold:
//   bias = raw*(inv*c1) + (c0 - mn*inv*c1)
// plain-exp softmax (scores bounded |s| <~ 10, fp32 exp safe)
__global__ __launch_bounds__(128) void k_attn(const float* __restrict__ q0, const float* __restrict__ k0,
                                              const float* __restrict__ v0, const float* __restrict__ q1,
                                              const float* __restrict__ k1, const float* __restrict__ v1,
                                              const float* __restrict__ data, const float* __restrict__ stats,
                                              const float* __restrict__ c1c0, int lj_base,
                                              float* __restrict__ att0, float* __restrict__ att1) {
    int bh = blockIdx.x;
    int b = bh >> 4, h = bh & 15;
    int nc = blockIdx.y;
    int j = blockIdx.z;
    const float* q = j ? q1 : q0;
    const float* k = j ? k1 : k0;
    const float* v = j ? v1 : v0;
    float mn = stats[b], inv = stats[4 + b];
    float c1 = c1c0[(lj_base + j) * 16 + h];
    float c0 = c1c0[160 + (lj_base + j) * 16 + h];
    float c1p = inv * c1;
    float c0p = c0 - mn * c1p;

    __shared__ float kl[256][20];
    __shared__ float vl[256][20];
    int t = threadIdx.x;
    for (int m = t; m < 256; m += 128) {
        const float* kp = k + ((size_t)(b * NN + m) * E) + h * DD;
        const float* vp = v + ((size_t)(b * NN + m) * E) + h * DD;
        #pragma unroll
        for (int d4 = 0; d4 < 4; d4++) {
            *(float4*)&kl[m][d4 * 4] = *(const float4*)(kp + d4 * 4);
            *(float4*)&vl[m][d4 * 4] = *(const float4*)(vp + d4 * 4);
        }
    }
    __syncthreads();

    int n = nc * 128 + t;
    float qr[16];
    const float* qp = q + ((size_t)(b * NN + n) * E) + h * DD;
    #pragma unroll
    for (int d4 = 0; d4 < 4; d4++) {
        float4 q4 = *(const float4*)(qp + d4 * 4);
        qr[d4 * 4 + 0] = q4.x; qr[d4 * 4 + 1] = q4.y; qr[d4 * 4 + 2] = q4.z; qr[d4 * 4 + 3] = q4.w;
    }
    // j==0: edge[n][m] = data[b][n][m];  j==1: edge^T[n][m] = data[b][m][n]
    const float* pedge = data + (size_t)b * NN * NN + (j ? n : n * NN);
    int estride = j ? NN : 1;

    float sum = 0.f;
    float acc[16] = {};
    for (int m = 0; m < 256; m++) {
        float s = 0.f;
        #pragma unroll
        for (int d = 0; d < 16; d++) s += qr[d] * kl[m][d];
        s = s * 0.25f + pedge[m * estride] * c1p + c0p;
        float e = __expf(s);
        sum += e;
        #pragma unroll
        for (int d = 0; d < 16; d++) acc[d] += e * vl[m][d];
    }
    float invs = 1.f / sum;
    float* op = (j ? att1 : att0) + ((size_t)(b * NN + n) * E) + h * DD;
    #pragma unroll
    for (int d = 0; d < 16; d++) op[d] = acc[d] * invs;
}

// ---------------- instance norm over node dim ----------------
// grid: (B, 2 j, 4 e-chunks), block 256 (4 n-slices x 64 channels)
__global__ __launch_bounds__(256) void k_inorm(const float* __restrict__ Y0, const float* __restrict__ Y1,
                                               const float* __restrict__ wl, const float* __restrict__ bl,
                                               int pstride, float* __restrict__ O0, float* __restrict__ O1,
                                               float* __restrict__ fout) {
    int b = blockIdx.x, j = blockIdx.y;
    int ec = blockIdx.z * 64;
    const float* Y = (j ? Y1 : Y0) + (size_t)b * NN * E;
    float* O = (j ? O1 : O0) + (size_t)b * NN * E;
    const float* w = wl + (size_t)j * pstride;
    const float* bbp = bl + (size_t)j * pstride;
    int t = threadIdx.x;
    int e = ec + (t & 63), n0 = t >> 6;
    float s = 0.f, s2 = 0.f;
    for (int n = n0; n < NN; n += 4) {
        float v = Y[(size_t)n * E + e];
        s += v;
        s2 += v * v;
    }
    __shared__ float ps[4][64], ps2[4][64];
    ps[n0][t & 63] = s;
    ps2[n0][t & 63] = s2;
    __syncthreads();
    float st = ps[0][t & 63] + ps[1][t & 63] + ps[2][t & 63] + ps[3][t & 63];
    float st2 = ps2[0][t & 63] + ps2[1][t & 63] + ps2[2][t & 63] + ps2[3][t & 63];
    float mu = st * (1.f / NN);
    float var = st2 * (1.f / NN) - mu * mu;
    var = fmaxf(var, 0.f);
    float scale = w[e] * rsqrtf(var + 1e-5f);
    float shift = bbp[e] - mu * scale;
    for (int n = n0; n < NN; n += 4) {
        float v = Y[(size_t)n * E + e] * scale + shift;
        O[(size_t)n * E + e] = v;
        if (fout) fout[(size_t)j * (BB * NN * E) + (size_t)b * NN * E + (size_t)n * E + e] = v;
    }
}

// ---------------- host ----------------
// Workspace (T = 262144 floats = 1 MB each), total 10 T + ~2 KB:
//   0: row   1: col
//   2: q0 / y0 / y20     3: q1 / y1 / y21
//   4: k0 / o10          5: k1 / o11
//   6-7:  v0,v1  -> ffh0 (2T contiguous; v dead after attn)
//   8-9:  att0,att1 -> ffh1 (2T contiguous; att dead after comb)
//   10T: stats(8) pmin(64) pmax(64) c1c0(320)
// Liveness verified per stage: no region is read after being reused.

extern "C" void kernel_launch(void* const* d_in, const int* in_sizes, int n_in,
                              void* d_out, int out_size, void* d_ws, size_t ws_size,
                              hipStream_t stream) {
    const float* data      = (const float*)d_in[0];
    const float* node_rand = (const float*)d_in[1];
    const float* Wnode     = (const float*)d_in[2];
    const float* bnode     = (const float*)d_in[3];
    const float* Wedge     = (const float*)d_in[4];
    const float* bedge     = (const float*)d_in[5];
    const float* Wq        = (const float*)d_in[6];
    const float* Wk        = (const float*)d_in[7];
    const float* Wv        = (const float*)d_in[8];
    const float* Wcomb     = (const float*)d_in[9];
    const float* bcomb     = (const float*)d_in[10];
    const float* n1w       = (const float*)d_in[11];
    const float* n1b       = (const float*)d_in[12];
    const float* W1        = (const float*)d_in[13];
    const float* b1        = (const float*)d_in[14];
    const float* W2        = (const float*)d_in[15];
    const float* b2        = (const float*)d_in[16];
    const float* n2w       = (const float*)d_in[17];
    const float* n2b       = (const float*)d_in[18];
    const float* Wmix      = (const float*)d_in[19];
    float* out = (float*)d_out;  // (row, col) concat: row @ 0, col @ B*N*E

    float* ws = (float*)d_ws;
    const size_t T = (size_t)MROWS * E;  // 262144 floats
    float* row  = ws + 0 * T;
    float* col  = ws + 1 * T;
    float* q0   = ws + 2 * T;
    float* q1   = ws + 3 * T;
    float* k0   = ws + 4 * T;
    float* k1   = ws + 5 * T;
    float* v0   = ws + 6 * T;
    float* v1   = ws + 7 * T;
    float* att0 = ws + 8 * T;
    float* att1 = ws + 9 * T;
    float* stats = ws + 10 * T;
    float* pmin  = ws + 10 * T + 8;
    float* pmax  = ws + 10 * T + 72;
    float* c1c0  = ws + 10 * T + 136;
    // aliases (liveness-checked)
    float* y0  = q0;  float* y1  = q1;    // comb out (q dead after attn)
    float* o10 = k0;  float* o11 = k1;    // IN1 out (k dead after attn)
    float* ffh0 = v0;                      // 2T: v0+v1 (v dead after attn)
    float* ffh1 = att0;                    // 2T: att0+att1 (att dead after comb)
    float* y20 = q0;  float* y21 = q1;    // FF2 out (y dead after IN1)

    k_minmax1<<<dim3(BB, 16), 256, 0, stream>>>(data, pmin, pmax);
    k_final<<<1, 256, 0, stream>>>(pmin, pmax, Wedge, bedge, Wmix, stats, c1c0);
    k_emb<<<(BB * NN * E) / 256, 256, 0, stream>>>(node_rand, Wnode, bnode, row, col);

    for (int l = 0; l < LAYERS; l++) {
        const float* Wq_l = Wq + (size_t)l * 2 * E * E;
        const float* Wk_l = Wk + (size_t)l * 2 * E * E;
        const float* Wv_l = Wv + (size_t)l * 2 * E * E;

        k_qkv<<<dim3(16, 4, 6), 256, 0, stream>>>(row, col, Wq_l, Wk_l, Wv_l,
                                                  q0, k0, v0, q1, k1, v1);
        k_attn<<<dim3(64, 2, 2), 128, 0, stream>>>(q0, k0, v0, q1, k1, v1, data, stats,
                                                   c1c0, l * 2, att0, att1);
        k_gemm2<<<dim3(16, 4, 2), 256, 0, stream>>>(att0, att1, Wcomb + (size_t)l * 2 * E * E, E * E,
                                                    bcomb + (size_t)l * 2 * E, E, row, col,
                                                    y0, y1, E, E, 0);
        k_inorm<<<dim3(BB, 2, 4), 256, 0, stream>>>(y0, y1, n1w + (size_t)l * 2 * E, n1b + (size_t)l * 2 * E,
                                                    E, o10, o11, nullptr);
        k_gemm2<<<dim3(16, 8, 2), 256, 0, stream>>>(o10, o11, W1 + (size_t)l * 2 * E * FFH, E * FFH,
                                                    b1 + (size_t)l * 2 * FFH, FFH, nullptr, nullptr,
                                                    ffh0, ffh1, E, FFH, 1);
        k_gemm2<<<dim3(16, 4, 2), 256, 0, stream>>>(ffh0, ffh1, W2 + (size_t)l * 2 * FFH * E, FFH * E,
                                                    b2 + (size_t)l * 2 * E, E, o10, o11,
                                                    q0 /*y20*/, q1 /*y21*/, FFH, E, 0);
        k_inorm<<<dim3(BB, 2, 4), 256, 0, stream>>>(y20, y21, n2w + (size_t)l * 2 * E, n2b + (size_t)l * 2 * E,
                                                    E, row, col, (l == LAYERS - 1) ? out : nullptr);
    }
}

// Round 5
// 580.338 us; speedup vs baseline: 2.1177x; 1.9003x over previous
//
#include <hip/hip_runtime.h>
#include <hip/hip_bf16.h>

#define E 256
#define H 16
#define DD 16
#define FFH 512
#define LAYERS 5
#define BB 4
#define NN 256
#define MROWS 1024  // B*N

// ---------------- prep: two-stage min/max ----------------
__global__ void k_minmax1(const float* __restrict__ data, float* __restrict__ pmin,
                          float* __restrict__ pmax) {
    int b = blockIdx.x, p = blockIdx.y;
    const float* src = data + (size_t)b * NN * NN + p * 4096;
    float lmin = 1e30f, lmax = -1e30f;
    #pragma unroll
    for (int i = 0; i < 16; i++) {
        float v = src[threadIdx.x + i * 256];
        lmin = fminf(lmin, v);
        lmax = fmaxf(lmax, v);
    }
    #pragma unroll
    for (int off = 32; off; off >>= 1) {
        lmin = fminf(lmin, __shfl_down(lmin, off));
        lmax = fmaxf(lmax, __shfl_down(lmax, off));
    }
    __shared__ float smin[4], smax[4];
    int wid = threadIdx.x >> 6, lane = threadIdx.x & 63;
    if (lane == 0) { smin[wid] = lmin; smax[wid] = lmax; }
    __syncthreads();
    if (threadIdx.x == 0) {
        pmin[b * 16 + p] = fminf(fminf(smin[0], smin[1]), fminf(smin[2], smin[3]));
        pmax[b * 16 + p] = fmaxf(fmaxf(smax[0], smax[1]), fmaxf(smax[2], smax[3]));
    }
}

// stage 2 (1 block): t<4 -> stats[b]; t in [64,224) -> mix constants
__global__ void k_final(const float* __restrict__ pmin, const float* __restrict__ pmax,
                        const float* __restrict__ Wedge, const float* __restrict__ bedge,
                        const float* __restrict__ Wmix, float* __restrict__ stats,
                        float* __restrict__ c1c0) {
    int t = threadIdx.x;
    if (t < 4) {
        float mn = 1e30f, mx = -1e30f;
        #pragma unroll
        for (int p = 0; p < 16; p++) {
            mn = fminf(mn, pmin[t * 16 + p]);
            mx = fmaxf(mx, pmax[t * 16 + p]);
        }
        float rng = mx - mn;
        if (rng == 0.f) rng = 1.f;
        stats[t] = mn;
        stats[4 + t] = 1.f / rng;
    } else if (t >= 64 && t < 64 + LAYERS * 2 * H) {
        int p = t - 64;
        int lj = p >> 4, h = p & 15;
        float c1 = 0.f, c0 = 0.f;
        for (int e = 0; e < E; e++) {
            float wm = Wmix[(lj * E + e) * H + h];
            c1 += Wedge[e] * wm;
            c0 += bedge[e] * wm;
        }
        c1c0[p] = c1;
        c1c0[160 + p] = c0;
    }
}

__global__ void k_emb(const float* __restrict__ node_rand, const float* __restrict__ Wnode,
                      const float* __restrict__ bnode, float* __restrict__ rowb,
                      float* __restrict__ colb) {
    int idx = blockIdx.x * 256 + threadIdx.x;
    int bn = idx >> 8, e = idx & 255;
    float v = node_rand[bn] * Wnode[e] + bnode[e];
    rowb[idx] = v;
    colb[idx] = v;
}

// 32x32 tile transpose of data[b] -> dataT[b]; grid (8,8,BB), 256 thr
__global__ __launch_bounds__(256) void k_dataT(const float* __restrict__ data,
                                               float* __restrict__ dataT) {
    __shared__ float tile[32][33];
    int b = blockIdx.z;
    int r0 = blockIdx.y * 32, c0 = blockIdx.x * 32;
    int tx = threadIdx.x & 31, ty = threadIdx.x >> 5;  // ty in [0,8)
    const float* src = data + (size_t)b * NN * NN;
    float* dst = dataT + (size_t)b * NN * NN;
    #pragma unroll
    for (int i = 0; i < 4; i++)
        tile[ty + 8 * i][tx] = src[(size_t)(r0 + ty + 8 * i) * NN + c0 + tx];
    __syncthreads();
    #pragma unroll
    for (int i = 0; i < 4; i++)
        dst[(size_t)(c0 + ty + 8 * i) * NN + r0 + tx] = tile[tx][ty + 8 * i];
}

// ---------------- fp32 GEMM: A [1024,K] x W [K,Ncols]; tile 32(M)x64(N) ----------------
// 256 thr, 8 acc/thread (2m x 4n), register prefetch of next K-slab.
// grid.x = 1024/32 = 32, grid.y = Ncols/64

__device__ __forceinline__ void gemm_dev(const float* __restrict__ A, const float* __restrict__ W,
                                         const float* __restrict__ bias, const float* __restrict__ R,
                                         float* __restrict__ C, int K, int Ncols, int relu) {
    __shared__ float As[16][34];  // [kk][m]
    __shared__ float Ws[16][68];  // [kk][n]
    int tid = threadIdx.x;
    int tx = tid & 15, ty = tid >> 4;  // tx: n-quad, ty: m-pair
    int mBase = blockIdx.x * 32, nBase = blockIdx.y * 64;
    int am = tid >> 4, ak = tid & 15;        // A staging: m=am(+16), kk=ak
    int wk = tid >> 4, wn = (tid & 15) * 4;  // W staging: row wk, 4 cols at wn
    float a0 = A[(size_t)(mBase + am) * K + ak];
    float a1 = A[(size_t)(mBase + am + 16) * K + ak];
    float4 w4 = *(const float4*)&W[(size_t)wk * Ncols + nBase + wn];
    float acc[2][4] = {};
    for (int kt = 0; kt < K; kt += 16) {
        __syncthreads();
        As[ak][am] = a0;
        As[ak][am + 16] = a1;
        *(float4*)&Ws[wk][wn] = w4;
        __syncthreads();
        if (kt + 16 < K) {
            a0 = A[(size_t)(mBase + am) * K + kt + 16 + ak];
            a1 = A[(size_t)(mBase + am + 16) * K + kt + 16 + ak];
            w4 = *(const float4*)&W[(size_t)(kt + 16 + wk) * Ncols + nBase + wn];
        }
        #pragma unroll
        for (int kk = 0; kk < 16; kk++) {
            float2 a2 = *(const float2*)&As[kk][ty * 2];
            float4 b4 = *(const float4*)&Ws[kk][tx * 4];
            acc[0][0] += a2.x * b4.x; acc[0][1] += a2.x * b4.y;
            acc[0][2] += a2.x * b4.z; acc[0][3] += a2.x * b4.w;
            acc[1][0] += a2.y * b4.x; acc[1][1] += a2.y * b4.y;
            acc[1][2] += a2.y * b4.z; acc[1][3] += a2.y * b4.w;
        }
    }
    int cBase = nBase + tx * 4;
    float4 bia = make_float4(0.f, 0.f, 0.f, 0.f);
    if (bias) bia = *(const float4*)&bias[cBase];
    #pragma unroll
    for (int i = 0; i < 2; i++) {
        int r = mBase + ty * 2 + i;
        float4 o = make_float4(acc[i][0] + bia.x, acc[i][1] + bia.y,
                               acc[i][2] + bia.z, acc[i][3] + bia.w);
        if (R) {
            float4 r4 = *(const float4*)&R[(size_t)r * Ncols + cBase];
            o.x += r4.x; o.y += r4.y; o.z += r4.z; o.w += r4.w;
        }
        if (relu) {
            o.x = fmaxf(o.x, 0.f); o.y = fmaxf(o.y, 0.f);
            o.z = fmaxf(o.z, 0.f); o.w = fmaxf(o.w, 0.f);
        }
        *(float4*)&C[(size_t)r * Ncols + cBase] = o;
    }
}

// z = j*3 + which(q/k/v); grid (32,4,6)
__global__ __launch_bounds__(256) void k_qkv(const float* __restrict__ row, const float* __restrict__ col,
                                             const float* __restrict__ Wq_l, const float* __restrict__ Wk_l,
                                             const float* __restrict__ Wv_l,
                                             float* q0, float* k0, float* v0,
                                             float* q1, float* k1, float* v1) {
    int z = blockIdx.z;
    int j = z / 3, w = z % 3;
    const float* A = (w == 0) ? (j == 0 ? row : col) : (j == 0 ? col : row);
    const float* W = (w == 0 ? Wq_l : (w == 1 ? Wk_l : Wv_l)) + (size_t)j * E * E;
    float* outs[6] = {q0, k0, v0, q1, k1, v1};
    gemm_dev(A, W, nullptr, nullptr, outs[z], E, E, 0);
}

__global__ __launch_bounds__(256) void k_gemm2(const float* __restrict__ A0, const float* __restrict__ A1,
                                               const float* __restrict__ Wl, int wstride,
                                               const float* __restrict__ biasl, int bstride,
                                               const float* __restrict__ R0, const float* __restrict__ R1,
                                               float* O0, float* O1, int K, int Ncols, int relu) {
    int j = blockIdx.z;
    gemm_dev(j ? A1 : A0, Wl + (size_t)j * wstride, biasl ? biasl + (size_t)j * bstride : nullptr,
             (R0 == nullptr) ? nullptr : (j ? R1 : R0), j ? O1 : O0, K, Ncols, relu);
}

// ---------------- fused attention ----------------
// grid (B*H=64, 8 n-groups of 32, 2 j), 256 thr (4 waves).
// 8 lanes per row: lane = r*8 + ml; lane ml handles m = ml + 8*i, i<32.
// K/V staged in LDS as [m][20] (padded rows, b128-aligned, conflict-free).
// Edge bias read from data (j=0) / dataT (j=1) with per-batch affine fold.
__global__ __launch_bounds__(256) void k_attn(const float* __restrict__ q0, const float* __restrict__ k0,
                                              const float* __restrict__ v0, const float* __restrict__ q1,
                                              const float* __restrict__ k1, const float* __restrict__ v1,
                                              const float* __restrict__ data, const float* __restrict__ dataT,
                                              const float* __restrict__ stats,
                                              const float* __restrict__ c1c0, int lj_base,
                                              float* __restrict__ att0, float* __restrict__ att1) {
    int bh = blockIdx.x;
    int b = bh >> 4, h = bh & 15;
    int ng = blockIdx.y;
    int j = blockIdx.z;
    const float* q = j ? q1 : q0;
    const float* k = j ? k1 : k0;
    const float* v = j ? v1 : v0;
    float mn = stats[b], inv = stats[4 + b];
    float c1 = c1c0[(lj_base + j) * 16 + h];
    float c0 = c1c0[160 + (lj_base + j) * 16 + h];
    float c1p = inv * c1;
    float c0p = c0 - mn * c1p;

    __shared__ float kl[256][20];
    __shared__ float vl[256][20];
    int t = threadIdx.x;
    {
        int c = t & 3, mb = t >> 2;
        #pragma unroll
        for (int it = 0; it < 4; it++) {
            int m = mb + 64 * it;
            const float* kp = k + ((size_t)(b * NN + m) * E) + h * DD + c * 4;
            const float* vp = v + ((size_t)(b * NN + m) * E) + h * DD + c * 4;
            *(float4*)&kl[m][c * 4] = *(const float4*)kp;
            *(float4*)&vl[m][c * 4] = *(const float4*)vp;
        }
    }
    __syncthreads();

    int lane = t & 63, w = t >> 6;
    int r = lane >> 3, ml = lane & 7;
    int n = ng * 32 + w * 8 + r;

    float qr[16];
    const float* qp = q + ((size_t)(b * NN + n) * E) + h * DD;
    #pragma unroll
    for (int d4 = 0; d4 < 4; d4++) {
        float4 q4 = *(const float4*)(qp + d4 * 4);
        qr[d4 * 4 + 0] = q4.x; qr[d4 * 4 + 1] = q4.y;
        qr[d4 * 4 + 2] = q4.z; qr[d4 * 4 + 3] = q4.w;
    }
    const float* pedge = (j ? dataT : data) + (size_t)b * NN * NN + (size_t)n * NN;

    float sum = 0.f;
    float acc[16] = {};
    for (int i = 0; i < 32; i++) {
        int m = ml + 8 * i;
        float4 ka = *(const float4*)&kl[m][0];
        float4 kb = *(const float4*)&kl[m][4];
        float4 kc = *(const float4*)&kl[m][8];
        float4 kd = *(const float4*)&kl[m][12];
        float s0 = qr[0] * ka.x + qr[1] * ka.y + qr[2] * ka.z + qr[3] * ka.w;
        float s1 = qr[4] * kb.x + qr[5] * kb.y + qr[6] * kb.z + qr[7] * kb.w;
        float s2 = qr[8] * kc.x + qr[9] * kc.y + qr[10] * kc.z + qr[11] * kc.w;
        float s3 = qr[12] * kd.x + qr[13] * kd.y + qr[14] * kd.z + qr[15] * kd.w;
        float s = ((s0 + s1) + (s2 + s3)) * 0.25f + pedge[m] * c1p + c0p;
        float e = __expf(s);
        sum += e;
        float4 va = *(const float4*)&vl[m][0];
        float4 vb = *(const float4*)&vl[m][4];
        float4 vc = *(const float4*)&vl[m][8];
        float4 vd = *(const float4*)&vl[m][12];
        acc[0] += e * va.x;  acc[1] += e * va.y;  acc[2] += e * va.z;  acc[3] += e * va.w;
        acc[4] += e * vb.x;  acc[5] += e * vb.y;  acc[6] += e * vb.z;  acc[7] += e * vb.w;
        acc[8] += e * vc.x;  acc[9] += e * vc.y;  acc[10] += e * vc.z; acc[11] += e * vc.w;
        acc[12] += e * vd.x; acc[13] += e * vd.y; acc[14] += e * vd.z; acc[15] += e * vd.w;
    }
    #pragma unroll
    for (int mask = 1; mask <= 4; mask <<= 1) {
        sum += __shfl_xor(sum, mask);
        #pragma unroll
        for (int d = 0; d < 16; d++) acc[d] += __shfl_xor(acc[d], mask);
    }
    if (ml == 0) {
        float invs = 1.f / sum;
        float* op = (j ? att1 : att0) + ((size_t)(b * NN + n) * E) + h * DD;
        *(float4*)(op + 0)  = make_float4(acc[0] * invs, acc[1] * invs, acc[2] * invs, acc[3] * invs);
        *(float4*)(op + 4)  = make_float4(acc[4] * invs, acc[5] * invs, acc[6] * invs, acc[7] * invs);
        *(float4*)(op + 8)  = make_float4(acc[8] * invs, acc[9] * invs, acc[10] * invs, acc[11] * invs);
        *(float4*)(op + 12) = make_float4(acc[12] * invs, acc[13] * invs, acc[14] * invs, acc[15] * invs);
    }
}

// ---------------- instance norm over node dim ----------------
// grid (B, 2 j, 32 e-chunks of 8), 256 thr (8 e x 32 n-slices); values reg-cached.
__global__ __launch_bounds__(256) void k_inorm(const float* __restrict__ Y0, const float* __restrict__ Y1,
                                               const float* __restrict__ wl, const float* __restrict__ bl,
                                               int pstride, float* __restrict__ O0, float* __restrict__ O1,
                                               float* __restrict__ fout) {
    int b = blockIdx.x, j = blockIdx.y;
    int ec = blockIdx.z * 8;
    const float* Y = (j ? Y1 : Y0) + (size_t)b * NN * E;
    float* O = (j ? O1 : O0) + (size_t)b * NN * E;
    const float* w = wl + (size_t)j * pstride;
    const float* bb = bl + (size_t)j * pstride;
    int t = threadIdx.x;
    int et = t & 7, n0 = t >> 3;  // n0 in [0,32)
    int e = ec + et;
    float vals[8];
    float s = 0.f, s2 = 0.f;
    #pragma unroll
    for (int kk = 0; kk < 8; kk++) {
        float v = Y[(size_t)(n0 + 32 * kk) * E + e];
        vals[kk] = v;
        s += v;
        s2 += v * v;
    }
    __shared__ float ps[32][9], ps2[32][9];
    ps[n0][et] = s;
    ps2[n0][et] = s2;
    __syncthreads();
    float st = 0.f, st2 = 0.f;
    #pragma unroll
    for (int kk = 0; kk < 32; kk++) { st += ps[kk][et]; st2 += ps2[kk][et]; }
    float mu = st * (1.f / NN);
    float var = fmaxf(st2 * (1.f / NN) - mu * mu, 0.f);
    float scale = w[e] * rsqrtf(var + 1e-5f);
    float shift = bb[e] - mu * scale;
    #pragma unroll
    for (int kk = 0; kk < 8; kk++) {
        float vv = vals[kk] * scale + shift;
        size_t idx = (size_t)(n0 + 32 * kk) * E + e;
        O[idx] = vv;
        if (fout) fout[(size_t)j * (BB * NN * E) + (size_t)b * NN * E + idx] = vv;
    }
}

// ---------------- host ----------------
// Workspace (T = 262144 floats = 1 MB each), total 11 T + ~2 KB:
//   0: dataT   1: row   2: col
//   3: q0 / y0 / y20     4: q1 / y1 / y21
//   5: k0 / o10          6: k1 / o11
//   7-8:  v0,v1  -> ffh0 (2T contiguous; v dead after attn)
//   9-10: att0,att1 -> ffh1 (2T contiguous; att dead after comb)
//   11T: stats(8) pmin(64) pmax(64) c1c0(320)

extern "C" void kernel_launch(void* const* d_in, const int* in_sizes, int n_in,
                              void* d_out, int out_size, void* d_ws, size_t ws_size,
                              hipStream_t stream) {
    const float* data      = (const float*)d_in[0];
    const float* node_rand = (const float*)d_in[1];
    const float* Wnode     = (const float*)d_in[2];
    const float* bnode     = (const float*)d_in[3];
    const float* Wedge     = (const float*)d_in[4];
    const float* bedge     = (const float*)d_in[5];
    const float* Wq        = (const float*)d_in[6];
    const float* Wk        = (const float*)d_in[7];
    const float* Wv        = (const float*)d_in[8];
    const float* Wcomb     = (const float*)d_in[9];
    const float* bcomb     = (const float*)d_in[10];
    const float* n1w       = (const float*)d_in[11];
    const float* n1b       = (const float*)d_in[12];
    const float* W1        = (const float*)d_in[13];
    const float* b1        = (const float*)d_in[14];
    const float* W2        = (const float*)d_in[15];
    const float* b2        = (const float*)d_in[16];
    const float* n2w       = (const float*)d_in[17];
    const float* n2b       = (const float*)d_in[18];
    const float* Wmix      = (const float*)d_in[19];
    float* out = (float*)d_out;  // (row, col) concat

    float* ws = (float*)d_ws;
    const size_t T = (size_t)MROWS * E;  // 262144 floats
    float* dataT = ws + 0 * T;
    float* row   = ws + 1 * T;
    float* col   = ws + 2 * T;
    float* q0    = ws + 3 * T;
    float* q1    = ws + 4 * T;
    float* k0    = ws + 5 * T;
    float* k1    = ws + 6 * T;
    float* v0    = ws + 7 * T;
    float* v1    = ws + 8 * T;
    float* att0  = ws + 9 * T;
    float* att1  = ws + 10 * T;
    float* stats = ws + 11 * T;
    float* pmin  = ws + 11 * T + 8;
    float* pmax  = ws + 11 * T + 72;
    float* c1c0  = ws + 11 * T + 136;
    // aliases (liveness-checked)
    float* y0  = q0;  float* y1  = q1;    // comb out (q dead after attn)
    float* o10 = k0;  float* o11 = k1;    // IN1 out (k dead after attn)
    float* ffh0 = v0;                      // 2T (v dead after attn)
    float* ffh1 = att0;                    // 2T (att dead after comb)
    float* y20 = q0;  float* y21 = q1;    // FF2 out (y dead after IN1)

    k_minmax1<<<dim3(BB, 16), 256, 0, stream>>>(data, pmin, pmax);
    k_final<<<1, 256, 0, stream>>>(pmin, pmax, Wedge, bedge, Wmix, stats, c1c0);
    k_emb<<<(BB * NN * E) / 256, 256, 0, stream>>>(node_rand, Wnode, bnode, row, col);
    k_dataT<<<dim3(8, 8, BB), 256, 0, stream>>>(data, dataT);

    for (int l = 0; l < LAYERS; l++) {
        const float* Wq_l = Wq + (size_t)l * 2 * E * E;
        const float* Wk_l = Wk + (size_t)l * 2 * E * E;
        const float* Wv_l = Wv + (size_t)l * 2 * E * E;

        k_qkv<<<dim3(32, 4, 6), 256, 0, stream>>>(row, col, Wq_l, Wk_l, Wv_l,
                                                  q0, k0, v0, q1, k1, v1);
        k_attn<<<dim3(64, 8, 2), 256, 0, stream>>>(q0, k0, v0, q1, k1, v1, data, dataT,
                                                   stats, c1c0, l * 2, att0, att1);
        k_gemm2<<<dim3(32, 4, 2), 256, 0, stream>>>(att0, att1, Wcomb + (size_t)l * 2 * E * E, E * E,
                                                    bcomb + (size_t)l * 2 * E, E, row, col,
                                                    y0, y1, E, E, 0);
        k_inorm<<<dim3(BB, 2, 32), 256, 0, stream>>>(y0, y1, n1w + (size_t)l * 2 * E, n1b + (size_t)l * 2 * E,
                                                     E, o10, o11, nullptr);
        k_gemm2<<<dim3(32, 8, 2), 256, 0, stream>>>(o10, o11, W1 + (size_t)l * 2 * E * FFH, E * FFH,
                                                    b1 + (size_t)l * 2 * FFH, FFH, nullptr, nullptr,
                                                    ffh0, ffh1, E, FFH, 1);
        k_gemm2<<<dim3(32, 4, 2), 256, 0, stream>>>(ffh0, ffh1, W2 + (size_t)l * 2 * FFH * E, FFH * E,
                                                    b2 + (size_t)l * 2 * E, E, o10, o11,
                                                    q0 /*y20*/, q1 /*y21*/, FFH, E, 0);
        k_inorm<<<dim3(BB, 2, 32), 256, 0, stream>>>(y20, y21, n2w + (size_t)l * 2 * E, n2b + (size_t)l * 2 * E,
                                                     E, row, col, (l == LAYERS - 1) ? out : nullptr);
    }
}

// Round 6
// 508.496 us; speedup vs baseline: 2.4169x; 1.1413x over previous
//
#include <hip/hip_runtime.h>
#include <hip/hip_bf16.h>

#define E 256
#define H 16
#define DD 16
#define FFH 512
#define LAYERS 5
#define BB 4
#define NN 256
#define MROWS 1024  // B*N

typedef __attribute__((ext_vector_type(8))) short bfrag;   // 8 bf16 (4 VGPRs)
typedef __attribute__((ext_vector_type(4))) float f32x4;   // MFMA acc

// ---------------- prep: two-stage min/max ----------------
__global__ void k_minmax1(const float* __restrict__ data, float* __restrict__ pmin,
                          float* __restrict__ pmax) {
    int b = blockIdx.x, p = blockIdx.y;
    const float* src = data + (size_t)b * NN * NN + p * 4096;
    float lmin = 1e30f, lmax = -1e30f;
    #pragma unroll
    for (int i = 0; i < 16; i++) {
        float v = src[threadIdx.x + i * 256];
        lmin = fminf(lmin, v);
        lmax = fmaxf(lmax, v);
    }
    #pragma unroll
    for (int off = 32; off; off >>= 1) {
        lmin = fminf(lmin, __shfl_down(lmin, off));
        lmax = fmaxf(lmax, __shfl_down(lmax, off));
    }
    __shared__ float smin[4], smax[4];
    int wid = threadIdx.x >> 6, lane = threadIdx.x & 63;
    if (lane == 0) { smin[wid] = lmin; smax[wid] = lmax; }
    __syncthreads();
    if (threadIdx.x == 0) {
        pmin[b * 16 + p] = fminf(fminf(smin[0], smin[1]), fminf(smin[2], smin[3]));
        pmax[b * 16 + p] = fmaxf(fmaxf(smax[0], smax[1]), fmaxf(smax[2], smax[3]));
    }
}

// stage 2 (1 block): t<4 -> stats[b]; t in [64,224) -> mix constants
__global__ void k_final(const float* __restrict__ pmin, const float* __restrict__ pmax,
                        const float* __restrict__ Wedge, const float* __restrict__ bedge,
                        const float* __restrict__ Wmix, float* __restrict__ stats,
                        float* __restrict__ c1c0) {
    int t = threadIdx.x;
    if (t < 4) {
        float mn = 1e30f, mx = -1e30f;
        #pragma unroll
        for (int p = 0; p < 16; p++) {
            mn = fminf(mn, pmin[t * 16 + p]);
            mx = fmaxf(mx, pmax[t * 16 + p]);
        }
        float rng = mx - mn;
        if (rng == 0.f) rng = 1.f;
        stats[t] = mn;
        stats[4 + t] = 1.f / rng;
    } else if (t >= 64 && t < 64 + LAYERS * 2 * H) {
        int p = t - 64;
        int lj = p >> 4, h = p & 15;
        float c1 = 0.f, c0 = 0.f;
        for (int e = 0; e < E; e++) {
            float wm = Wmix[(lj * E + e) * H + h];
            c1 += Wedge[e] * wm;
            c0 += bedge[e] * wm;
        }
        c1c0[p] = c1;
        c1c0[160 + p] = c0;
    }
}

__global__ void k_emb(const float* __restrict__ node_rand, const float* __restrict__ Wnode,
                      const float* __restrict__ bnode, float* __restrict__ rowb,
                      float* __restrict__ colb) {
    int idx = blockIdx.x * 256 + threadIdx.x;
    int bn = idx >> 8, e = idx & 255;
    float v = node_rand[bn] * Wnode[e] + bnode[e];
    rowb[idx] = v;
    colb[idx] = v;
}

// 32x32 tile transpose of data[b] -> dataT[b]; grid (8,8,BB), 256 thr
__global__ __launch_bounds__(256) void k_dataT(const float* __restrict__ data,
                                               float* __restrict__ dataT) {
    __shared__ float tile[32][33];
    int b = blockIdx.z;
    int r0 = blockIdx.y * 32, c0 = blockIdx.x * 32;
    int tx = threadIdx.x & 31, ty = threadIdx.x >> 5;
    const float* src = data + (size_t)b * NN * NN;
    float* dst = dataT + (size_t)b * NN * NN;
    #pragma unroll
    for (int i = 0; i < 4; i++)
        tile[ty + 8 * i][tx] = src[(size_t)(r0 + ty + 8 * i) * NN + c0 + tx];
    __syncthreads();
    #pragma unroll
    for (int i = 0; i < 4; i++)
        dst[(size_t)(c0 + ty + 8 * i) * NN + r0 + tx] = tile[tx][ty + 8 * i];
}

// ---------------- weight prep: fp32 [K][N] -> bf16 hi/lo, slab-packed [kslab][n][32] ----------------
// grid (nmat, K/32, N/64), 256 thr
__global__ __launch_bounds__(256) void k_wprep(const float* __restrict__ W,
                                               unsigned short* __restrict__ Dh,
                                               unsigned short* __restrict__ Dl,
                                               int K, int N) {
    int mat = blockIdx.x, s = blockIdx.y, nt = blockIdx.z;
    __shared__ unsigned short th[64][40], tl[64][40];
    int t = threadIdx.x;
    int kl = t >> 3, nl = (t & 7) * 8;
    const float* p = W + (size_t)mat * K * N + (size_t)(s * 32 + kl) * N + nt * 64 + nl;
    float4 f0 = *(const float4*)p;
    float4 f1 = *(const float4*)(p + 4);
    float fv[8] = {f0.x, f0.y, f0.z, f0.w, f1.x, f1.y, f1.z, f1.w};
    #pragma unroll
    for (int i = 0; i < 8; i++) {
        unsigned int u = __float_as_uint(fv[i]);
        unsigned short h = (unsigned short)((u + 0x7fffu + ((u >> 16) & 1u)) >> 16);
        float res = fv[i] - __uint_as_float((unsigned int)h << 16);
        unsigned int u2 = __float_as_uint(res);
        th[nl + i][kl] = h;
        tl[nl + i][kl] = (unsigned short)((u2 + 0x7fffu + ((u2 >> 16) & 1u)) >> 16);
    }
    __syncthreads();
    int n = t >> 2, ko = (t & 3) * 8;
    size_t dbase = (size_t)mat * K * N + (size_t)s * N * 32 + (size_t)nt * 64 * 32
                 + (size_t)n * 32 + ko;
    *(ushort4*)(Dh + dbase)     = *(const ushort4*)&th[n][ko];
    *(ushort4*)(Dh + dbase + 4) = *(const ushort4*)&th[n][ko + 4];
    *(ushort4*)(Dl + dbase)     = *(const ushort4*)&tl[n][ko];
    *(ushort4*)(Dl + dbase + 4) = *(const ushort4*)&tl[n][ko + 4];
}

// ---------------- MFMA GEMM (3x bf16 split ~= fp32): A fp32 [1024][K] x W [K][N] ----------------
// block 256 thr = 4 waves; tile 64(M)x64(N); wave -> 32x32 (2x2 16x16 MFMA tiles)
// grid.x = 1024/64 = 16, grid.y = N/64
__device__ __forceinline__ void mfma_gemm(const float* __restrict__ A,
                                          const unsigned short* __restrict__ Bh,
                                          const unsigned short* __restrict__ Bl,
                                          const float* __restrict__ bias,
                                          const float* __restrict__ R,
                                          float* __restrict__ C, int K, int Ncols, int relu) {
    __shared__ unsigned short AsH[64][40], AsL[64][40], BsH[64][40], BsL[64][40];
    int t = threadIdx.x;
    int lane = t & 63, wave = t >> 6;
    int quad = lane >> 4, l16 = lane & 15;
    int wy = wave >> 1, wx = wave & 1;
    int mBase = blockIdx.x * 64, nBase = blockIdx.y * 64;
    f32x4 acc00 = {0.f, 0.f, 0.f, 0.f}, acc01 = acc00, acc10 = acc00, acc11 = acc00;
    int ar = t >> 2, aks = (t & 3) * 8;
    const int nslab = K >> 5;
    for (int s = 0; s < nslab; s++) {
        const float* ap = A + (size_t)(mBase + ar) * K + s * 32 + aks;
        float4 a0 = *(const float4*)ap;
        float4 a1 = *(const float4*)(ap + 4);
        float av[8] = {a0.x, a0.y, a0.z, a0.w, a1.x, a1.y, a1.z, a1.w};
        unsigned short ah[8], al[8];
        #pragma unroll
        for (int i = 0; i < 8; i++) {
            unsigned int u = __float_as_uint(av[i]);
            unsigned short h = (unsigned short)((u + 0x7fffu + ((u >> 16) & 1u)) >> 16);
            ah[i] = h;
            float res = av[i] - __uint_as_float((unsigned int)h << 16);
            unsigned int u2 = __float_as_uint(res);
            al[i] = (unsigned short)((u2 + 0x7fffu + ((u2 >> 16) & 1u)) >> 16);
        }
        const unsigned short* bp = Bh + ((size_t)s * Ncols + nBase) * 32 + t * 8;
        const unsigned short* lp = Bl + ((size_t)s * Ncols + nBase) * 32 + t * 8;
        ushort4 bh0 = *(const ushort4*)bp;
        ushort4 bh1 = *(const ushort4*)(bp + 4);
        ushort4 bl0 = *(const ushort4*)lp;
        ushort4 bl1 = *(const ushort4*)(lp + 4);
        __syncthreads();
        *(ushort4*)&AsH[ar][aks]     = *(ushort4*)&ah[0];
        *(ushort4*)&AsH[ar][aks + 4] = *(ushort4*)&ah[4];
        *(ushort4*)&AsL[ar][aks]     = *(ushort4*)&al[0];
        *(ushort4*)&AsL[ar][aks + 4] = *(ushort4*)&al[4];
        *(ushort4*)&BsH[ar][aks]     = bh0;
        *(ushort4*)&BsH[ar][aks + 4] = bh1;
        *(ushort4*)&BsL[ar][aks]     = bl0;
        *(ushort4*)&BsL[ar][aks + 4] = bl1;
        __syncthreads();
        bfrag a_h0 = *(const bfrag*)&AsH[wy * 32 + l16][quad * 8];
        bfrag a_h1 = *(const bfrag*)&AsH[wy * 32 + 16 + l16][quad * 8];
        bfrag a_l0 = *(const bfrag*)&AsL[wy * 32 + l16][quad * 8];
        bfrag a_l1 = *(const bfrag*)&AsL[wy * 32 + 16 + l16][quad * 8];
        bfrag b_h0 = *(const bfrag*)&BsH[wx * 32 + l16][quad * 8];
        bfrag b_h1 = *(const bfrag*)&BsH[wx * 32 + 16 + l16][quad * 8];
        bfrag b_l0 = *(const bfrag*)&BsL[wx * 32 + l16][quad * 8];
        bfrag b_l1 = *(const bfrag*)&BsL[wx * 32 + 16 + l16][quad * 8];
        acc00 = __builtin_amdgcn_mfma_f32_16x16x32_bf16(a_h0, b_h0, acc00, 0, 0, 0);
        acc01 = __builtin_amdgcn_mfma_f32_16x16x32_bf16(a_h0, b_h1, acc01, 0, 0, 0);
        acc10 = __builtin_amdgcn_mfma_f32_16x16x32_bf16(a_h1, b_h0, acc10, 0, 0, 0);
        acc11 = __builtin_amdgcn_mfma_f32_16x16x32_bf16(a_h1, b_h1, acc11, 0, 0, 0);
        acc00 = __builtin_amdgcn_mfma_f32_16x16x32_bf16(a_h0, b_l0, acc00, 0, 0, 0);
        acc01 = __builtin_amdgcn_mfma_f32_16x16x32_bf16(a_h0, b_l1, acc01, 0, 0, 0);
        acc10 = __builtin_amdgcn_mfma_f32_16x16x32_bf16(a_h1, b_l0, acc10, 0, 0, 0);
        acc11 = __builtin_amdgcn_mfma_f32_16x16x32_bf16(a_h1, b_l1, acc11, 0, 0, 0);
        acc00 = __builtin_amdgcn_mfma_f32_16x16x32_bf16(a_l0, b_h0, acc00, 0, 0, 0);
        acc01 = __builtin_amdgcn_mfma_f32_16x16x32_bf16(a_l0, b_h1, acc01, 0, 0, 0);
        acc10 = __builtin_amdgcn_mfma_f32_16x16x32_bf16(a_l1, b_h0, acc10, 0, 0, 0);
        acc11 = __builtin_amdgcn_mfma_f32_16x16x32_bf16(a_l1, b_h1, acc11, 0, 0, 0);
    }
    int col0 = nBase + wx * 32 + l16;
    int col1 = col0 + 16;
    float bia0 = bias ? bias[col0] : 0.f;
    float bia1 = bias ? bias[col1] : 0.f;
    #pragma unroll
    for (int r = 0; r < 4; r++) {
        int row0 = mBase + wy * 32 + quad * 4 + r;
        int row1 = row0 + 16;
        float v;
        v = acc00[r] + bia0; if (R) v += R[(size_t)row0 * Ncols + col0]; if (relu) v = fmaxf(v, 0.f);
        C[(size_t)row0 * Ncols + col0] = v;
        v = acc01[r] + bia1; if (R) v += R[(size_t)row0 * Ncols + col1]; if (relu) v = fmaxf(v, 0.f);
        C[(size_t)row0 * Ncols + col1] = v;
        v = acc10[r] + bia0; if (R) v += R[(size_t)row1 * Ncols + col0]; if (relu) v = fmaxf(v, 0.f);
        C[(size_t)row1 * Ncols + col0] = v;
        v = acc11[r] + bia1; if (R) v += R[(size_t)row1 * Ncols + col1]; if (relu) v = fmaxf(v, 0.f);
        C[(size_t)row1 * Ncols + col1] = v;
    }
}

// z = j*3 + which(q/k/v); grid (16,4,6)
__global__ __launch_bounds__(256) void k_qkv(const float* __restrict__ row, const float* __restrict__ col,
                                             const unsigned short* __restrict__ WqTh, const unsigned short* __restrict__ WqTl,
                                             const unsigned short* __restrict__ WkTh, const unsigned short* __restrict__ WkTl,
                                             const unsigned short* __restrict__ WvTh, const unsigned short* __restrict__ WvTl,
                                             int lbase2,
                                             float* q0, float* k0, float* v0,
                                             float* q1, float* k1, float* v1) {
    int z = blockIdx.z;
    int j = z / 3, w = z % 3;
    const float* A = (w == 0) ? (j == 0 ? row : col) : (j == 0 ? col : row);
    const unsigned short* Wh = (w == 0 ? WqTh : (w == 1 ? WkTh : WvTh)) + (size_t)(lbase2 + j) * E * E;
    const unsigned short* Wl = (w == 0 ? WqTl : (w == 1 ? WkTl : WvTl)) + (size_t)(lbase2 + j) * E * E;
    float* outs[6] = {q0, k0, v0, q1, k1, v1};
    mfma_gemm(A, Wh, Wl, nullptr, nullptr, outs[z], E, E, 0);
}

__global__ __launch_bounds__(256) void k_gemm2(const float* __restrict__ A0, const float* __restrict__ A1,
                                               const unsigned short* __restrict__ Wh,
                                               const unsigned short* __restrict__ Wl,
                                               int lbase2, size_t wstride,
                                               const float* __restrict__ biasl, int bstride,
                                               const float* __restrict__ R0, const float* __restrict__ R1,
                                               float* O0, float* O1, int K, int Ncols, int relu) {
    int j = blockIdx.z;
    mfma_gemm(j ? A1 : A0,
              Wh + (size_t)(lbase2 + j) * wstride,
              Wl + (size_t)(lbase2 + j) * wstride,
              biasl ? biasl + (size_t)j * bstride : nullptr,
              (R0 == nullptr) ? nullptr : (j ? R1 : R0),
              j ? O1 : O0, K, Ncols, relu);
}

// ---------------- fused attention ----------------
// grid (B*H=64, 8 n-groups of 32, 2 j), 256 thr. 8 lanes cooperate per row.
__global__ __launch_bounds__(256) void k_attn(const float* __restrict__ q0, const float* __restrict__ k0,
                                              const float* __restrict__ v0, const float* __restrict__ q1,
                                              const float* __restrict__ k1, const float* __restrict__ v1,
                                              const float* __restrict__ data, const float* __restrict__ dataT,
                                              const float* __restrict__ stats,
                                              const float* __restrict__ c1c0, int lj_base,
                                              float* __restrict__ att0, float* __restrict__ att1) {
    int bh = blockIdx.x;
    int b = bh >> 4, h = bh & 15;
    int ng = blockIdx.y;
    int j = blockIdx.z;
    const float* q = j ? q1 : q0;
    const float* k = j ? k1 : k0;
    const float* v = j ? v1 : v0;
    float mn = stats[b], inv = stats[4 + b];
    float c1 = c1c0[(lj_base + j) * 16 + h];
    float c0 = c1c0[160 + (lj_base + j) * 16 + h];
    float c1p = inv * c1;
    float c0p = c0 - mn * c1p;

    __shared__ float kl[256][20];
    __shared__ float vl[256][20];
    int t = threadIdx.x;
    {
        int c = t & 3, mb = t >> 2;
        #pragma unroll
        for (int it = 0; it < 4; it++) {
            int m = mb + 64 * it;
            const float* kp = k + ((size_t)(b * NN + m) * E) + h * DD + c * 4;
            const float* vp = v + ((size_t)(b * NN + m) * E) + h * DD + c * 4;
            *(float4*)&kl[m][c * 4] = *(const float4*)kp;
            *(float4*)&vl[m][c * 4] = *(const float4*)vp;
        }
    }
    __syncthreads();

    int lane = t & 63, w = t >> 6;
    int r = lane >> 3, ml = lane & 7;
    int n = ng * 32 + w * 8 + r;

    float qr[16];
    const float* qp = q + ((size_t)(b * NN + n) * E) + h * DD;
    #pragma unroll
    for (int d4 = 0; d4 < 4; d4++) {
        float4 q4 = *(const float4*)(qp + d4 * 4);
        qr[d4 * 4 + 0] = q4.x; qr[d4 * 4 + 1] = q4.y;
        qr[d4 * 4 + 2] = q4.z; qr[d4 * 4 + 3] = q4.w;
    }
    const float* pedge = (j ? dataT : data) + (size_t)b * NN * NN + (size_t)n * NN;

    float sum = 0.f;
    float acc[16] = {};
    for (int i = 0; i < 32; i++) {
        int m = ml + 8 * i;
        float4 ka = *(const float4*)&kl[m][0];
        float4 kb = *(const float4*)&kl[m][4];
        float4 kc = *(const float4*)&kl[m][8];
        float4 kd = *(const float4*)&kl[m][12];
        float s0 = qr[0] * ka.x + qr[1] * ka.y + qr[2] * ka.z + qr[3] * ka.w;
        float s1 = qr[4] * kb.x + qr[5] * kb.y + qr[6] * kb.z + qr[7] * kb.w;
        float s2 = qr[8] * kc.x + qr[9] * kc.y + qr[10] * kc.z + qr[11] * kc.w;
        float s3 = qr[12] * kd.x + qr[13] * kd.y + qr[14] * kd.z + qr[15] * kd.w;
        float s = ((s0 + s1) + (s2 + s3)) * 0.25f + pedge[m] * c1p + c0p;
        float e = __expf(s);
        sum += e;
        float4 va = *(const float4*)&vl[m][0];
        float4 vb = *(const float4*)&vl[m][4];
        float4 vc = *(const float4*)&vl[m][8];
        float4 vd = *(const float4*)&vl[m][12];
        acc[0] += e * va.x;  acc[1] += e * va.y;  acc[2] += e * va.z;  acc[3] += e * va.w;
        acc[4] += e * vb.x;  acc[5] += e * vb.y;  acc[6] += e * vb.z;  acc[7] += e * vb.w;
        acc[8] += e * vc.x;  acc[9] += e * vc.y;  acc[10] += e * vc.z; acc[11] += e * vc.w;
        acc[12] += e * vd.x; acc[13] += e * vd.y; acc[14] += e * vd.z; acc[15] += e * vd.w;
    }
    #pragma unroll
    for (int mask = 1; mask <= 4; mask <<= 1) {
        sum += __shfl_xor(sum, mask);
        #pragma unroll
        for (int d = 0; d < 16; d++) acc[d] += __shfl_xor(acc[d], mask);
    }
    if (ml == 0) {
        float invs = 1.f / sum;
        float* op = (j ? att1 : att0) + ((size_t)(b * NN + n) * E) + h * DD;
        *(float4*)(op + 0)  = make_float4(acc[0] * invs, acc[1] * invs, acc[2] * invs, acc[3] * invs);
        *(float4*)(op + 4)  = make_float4(acc[4] * invs, acc[5] * invs, acc[6] * invs, acc[7] * invs);
        *(float4*)(op + 8)  = make_float4(acc[8] * invs, acc[9] * invs, acc[10] * invs, acc[11] * invs);
        *(float4*)(op + 12) = make_float4(acc[12] * invs, acc[13] * invs, acc[14] * invs, acc[15] * invs);
    }
}

// ---------------- instance norm over node dim ----------------
// grid (B, 2 j, 32 e-chunks of 8), 256 thr; values reg-cached.
__global__ __launch_bounds__(256) void k_inorm(const float* __restrict__ Y0, const float* __restrict__ Y1,
                                               const float* __restrict__ wl, const float* __restrict__ bl,
                                               int pstride, float* __restrict__ O0, float* __restrict__ O1,
                                               float* __restrict__ fout) {
    int b = blockIdx.x, j = blockIdx.y;
    int ec = blockIdx.z * 8;
    const float* Y = (j ? Y1 : Y0) + (size_t)b * NN * E;
    float* O = (j ? O1 : O0) + (size_t)b * NN * E;
    const float* w = wl + (size_t)j * pstride;
    const float* bb = bl + (size_t)j * pstride;
    int t = threadIdx.x;
    int et = t & 7, n0 = t >> 3;
    int e = ec + et;
    float vals[8];
    float s = 0.f, s2 = 0.f;
    #pragma unroll
    for (int kk = 0; kk < 8; kk++) {
        float v = Y[(size_t)(n0 + 32 * kk) * E + e];
        vals[kk] = v;
        s += v;
        s2 += v * v;
    }
    __shared__ float ps[32][9], ps2[32][9];
    ps[n0][et] = s;
    ps2[n0][et] = s2;
    __syncthreads();
    float st = 0.f, st2 = 0.f;
    #pragma unroll
    for (int kk = 0; kk < 32; kk++) { st += ps[kk][et]; st2 += ps2[kk][et]; }
    float mu = st * (1.f / NN);
    float var = fmaxf(st2 * (1.f / NN) - mu * mu, 0.f);
    float scale = w[e] * rsqrtf(var + 1e-5f);
    float shift = bb[e] - mu * scale;
    #pragma unroll
    for (int kk = 0; kk < 8; kk++) {
        float vv = vals[kk] * scale + shift;
        size_t idx = (size_t)(n0 + 32 * kk) * E + e;
        O[idx] = vv;
        if (fout) fout[(size_t)j * (BB * NN * E) + (size_t)b * NN * E + idx] = vv;
    }
}

// ---------------- host ----------------
// ws: 11 T floats (as R5) + 512 floats scalars + 21 MB bf16 weight cache.

extern "C" void kernel_launch(void* const* d_in, const int* in_sizes, int n_in,
                              void* d_out, int out_size, void* d_ws, size_t ws_size,
                              hipStream_t stream) {
    const float* data      = (const float*)d_in[0];
    const float* node_rand = (const float*)d_in[1];
    const float* Wnode     = (const float*)d_in[2];
    const float* bnode     = (const float*)d_in[3];
    const float* Wedge     = (const float*)d_in[4];
    const float* bedge     = (const float*)d_in[5];
    const float* Wq        = (const float*)d_in[6];
    const float* Wk        = (const float*)d_in[7];
    const float* Wv        = (const float*)d_in[8];
    const float* Wcomb     = (const float*)d_in[9];
    const float* bcomb     = (const float*)d_in[10];
    const float* n1w       = (const float*)d_in[11];
    const float* n1b       = (const float*)d_in[12];
    const float* W1        = (const float*)d_in[13];
    const float* b1        = (const float*)d_in[14];
    const float* W2        = (const float*)d_in[15];
    const float* b2        = (const float*)d_in[16];
    const float* n2w       = (const float*)d_in[17];
    const float* n2b       = (const float*)d_in[18];
    const float* Wmix      = (const float*)d_in[19];
    float* out = (float*)d_out;  // (row, col) concat

    float* ws = (float*)d_ws;
    const size_t T = (size_t)MROWS * E;  // 262144 floats
    float* dataT = ws + 0 * T;
    float* row   = ws + 1 * T;
    float* col   = ws + 2 * T;
    float* q0    = ws + 3 * T;
    float* q1    = ws + 4 * T;
    float* k0    = ws + 5 * T;
    float* k1    = ws + 6 * T;
    float* v0    = ws + 7 * T;
    float* v1    = ws + 8 * T;
    float* att0  = ws + 9 * T;
    float* att1  = ws + 10 * T;
    float* stats = ws + 11 * T;
    float* pmin  = ws + 11 * T + 8;
    float* pmax  = ws + 11 * T + 72;
    float* c1c0  = ws + 11 * T + 136;
    // bf16 weight cache region
    unsigned short* sh = (unsigned short*)(ws + 11 * T + 512);
    const size_t EE10 = (size_t)10 * E * E;       // 655360
    const size_t EF10 = (size_t)10 * E * FFH;     // 1310720
    unsigned short* WqTh = sh; sh += EE10;  unsigned short* WqTl = sh; sh += EE10;
    unsigned short* WkTh = sh; sh += EE10;  unsigned short* WkTl = sh; sh += EE10;
    unsigned short* WvTh = sh; sh += EE10;  unsigned short* WvTl = sh; sh += EE10;
    unsigned short* WcTh = sh; sh += EE10;  unsigned short* WcTl = sh; sh += EE10;
    unsigned short* W1Th = sh; sh += EF10;  unsigned short* W1Tl = sh; sh += EF10;
    unsigned short* W2Th = sh; sh += EF10;  unsigned short* W2Tl = sh; sh += EF10;
    // aliases (liveness-checked)
    float* y0  = q0;  float* y1  = q1;    // comb out (q dead after attn)
    float* o10 = k0;  float* o11 = k1;    // IN1 out (k dead after attn)
    float* ffh0 = v0;                      // 2T (v dead after attn)
    float* ffh1 = att0;                    // 2T (att dead after comb)
    float* y20 = q0;  float* y21 = q1;    // FF2 out (y dead after IN1)

    k_minmax1<<<dim3(BB, 16), 256, 0, stream>>>(data, pmin, pmax);
    k_final<<<1, 256, 0, stream>>>(pmin, pmax, Wedge, bedge, Wmix, stats, c1c0);
    k_emb<<<(BB * NN * E) / 256, 256, 0, stream>>>(node_rand, Wnode, bnode, row, col);
    k_dataT<<<dim3(8, 8, BB), 256, 0, stream>>>(data, dataT);
    k_wprep<<<dim3(10, 8, 4), 256, 0, stream>>>(Wq, WqTh, WqTl, E, E);
    k_wprep<<<dim3(10, 8, 4), 256, 0, stream>>>(Wk, WkTh, WkTl, E, E);
    k_wprep<<<dim3(10, 8, 4), 256, 0, stream>>>(Wv, WvTh, WvTl, E, E);
    k_wprep<<<dim3(10, 8, 4), 256, 0, stream>>>(Wcomb, WcTh, WcTl, E, E);
    k_wprep<<<dim3(10, 8, 8), 256, 0, stream>>>(W1, W1Th, W1Tl, E, FFH);
    k_wprep<<<dim3(10, 16, 4), 256, 0, stream>>>(W2, W2Th, W2Tl, FFH, E);

    for (int l = 0; l < LAYERS; l++) {
        k_qkv<<<dim3(16, 4, 6), 256, 0, stream>>>(row, col, WqTh, WqTl, WkTh, WkTl,
                                                  WvTh, WvTl, l * 2,
                                                  q0, k0, v0, q1, k1, v1);
        k_attn<<<dim3(64, 8, 2), 256, 0, stream>>>(q0, k0, v0, q1, k1, v1, data, dataT,
                                                   stats, c1c0, l * 2, att0, att1);
        k_gemm2<<<dim3(16, 4, 2), 256, 0, stream>>>(att0, att1, WcTh, WcTl, l * 2, (size_t)E * E,
                                                    bcomb + (size_t)l * 2 * E, E, row, col,
                                                    y0, y1, E, E, 0);
        k_inorm<<<dim3(BB, 2, 32), 256, 0, stream>>>(y0, y1, n1w + (size_t)l * 2 * E, n1b + (size_t)l * 2 * E,
                                                     E, o10, o11, nullptr);
        k_gemm2<<<dim3(16, 8, 2), 256, 0, stream>>>(o10, o11, W1Th, W1Tl, l * 2, (size_t)E * FFH,
                                                    b1 + (size_t)l * 2 * FFH, FFH, nullptr, nullptr,
                                                    ffh0, ffh1, E, FFH, 1);
        k_gemm2<<<dim3(16, 4, 2), 256, 0, stream>>>(ffh0, ffh1, W2Th, W2Tl, l * 2, (size_t)FFH * E,
                                                    b2 + (size_t)l * 2 * E, E, o10, o11,
                                                    q0 /*y20*/, q1 /*y21*/, FFH, E, 0);
        k_inorm<<<dim3(BB, 2, 32), 256, 0, stream>>>(y20, y21, n2w + (size_t)l * 2 * E, n2b + (size_t)l * 2 * E,
                                                     E, row, col, (l == LAYERS - 1) ? out : nullptr);
    }
}

// Round 7
// 460.933 us; speedup vs baseline: 2.6663x; 1.1032x over previous
//
#include <hip/hip_runtime.h>
#include <hip/hip_bf16.h>

#define E 256
#define H 16
#define DD 16
#define FFH 512
#define LAYERS 5
#define BB 4
#define NN 256
#define MROWS 1024  // B*N

typedef __attribute__((ext_vector_type(8))) short bfrag;          // 8 bf16 (4 VGPRs)
typedef __attribute__((ext_vector_type(4))) float f32x4;          // MFMA acc
typedef __attribute__((ext_vector_type(8))) unsigned short us8;   // 16B
typedef unsigned short u16;

__device__ __forceinline__ void bsplit(float v, u16& h, u16& l) {
    unsigned u = __float_as_uint(v);
    u16 hh = (u16)((u + 0x7fffu + ((u >> 16) & 1u)) >> 16);
    float r = v - __uint_as_float((unsigned)hh << 16);
    unsigned u2 = __float_as_uint(r);
    h = hh;
    l = (u16)((u2 + 0x7fffu + ((u2 >> 16) & 1u)) >> 16);
}

// ---------------- prep: two-stage min/max ----------------
__global__ void k_minmax1(const float* __restrict__ data, float* __restrict__ pmin,
                          float* __restrict__ pmax) {
    int b = blockIdx.x, p = blockIdx.y;
    const float* src = data + (size_t)b * NN * NN + p * 4096;
    float lmin = 1e30f, lmax = -1e30f;
    #pragma unroll
    for (int i = 0; i < 16; i++) {
        float v = src[threadIdx.x + i * 256];
        lmin = fminf(lmin, v);
        lmax = fmaxf(lmax, v);
    }
    #pragma unroll
    for (int off = 32; off; off >>= 1) {
        lmin = fminf(lmin, __shfl_down(lmin, off));
        lmax = fmaxf(lmax, __shfl_down(lmax, off));
    }
    __shared__ float smin[4], smax[4];
    int wid = threadIdx.x >> 6, lane = threadIdx.x & 63;
    if (lane == 0) { smin[wid] = lmin; smax[wid] = lmax; }
    __syncthreads();
    if (threadIdx.x == 0) {
        pmin[b * 16 + p] = fminf(fminf(smin[0], smin[1]), fminf(smin[2], smin[3]));
        pmax[b * 16 + p] = fmaxf(fmaxf(smax[0], smax[1]), fmaxf(smax[2], smax[3]));
    }
}

__global__ void k_final(const float* __restrict__ pmin, const float* __restrict__ pmax,
                        const float* __restrict__ Wedge, const float* __restrict__ bedge,
                        const float* __restrict__ Wmix, float* __restrict__ stats,
                        float* __restrict__ c1c0) {
    int t = threadIdx.x;
    if (t < 4) {
        float mn = 1e30f, mx = -1e30f;
        #pragma unroll
        for (int p = 0; p < 16; p++) {
            mn = fminf(mn, pmin[t * 16 + p]);
            mx = fmaxf(mx, pmax[t * 16 + p]);
        }
        float rng = mx - mn;
        if (rng == 0.f) rng = 1.f;
        stats[t] = mn;
        stats[4 + t] = 1.f / rng;
    } else if (t >= 64 && t < 64 + LAYERS * 2 * H) {
        int p = t - 64;
        int lj = p >> 4, h = p & 15;
        float c1 = 0.f, c0 = 0.f;
        for (int e = 0; e < E; e++) {
            float wm = Wmix[(lj * E + e) * H + h];
            c1 += Wedge[e] * wm;
            c0 += bedge[e] * wm;
        }
        c1c0[p] = c1;
        c1c0[160 + p] = c0;
    }
}

__global__ void k_emb(const float* __restrict__ node_rand, const float* __restrict__ Wnode,
                      const float* __restrict__ bnode, float* __restrict__ rowb,
                      float* __restrict__ colb, u16* __restrict__ rowh, u16* __restrict__ rowl,
                      u16* __restrict__ colh, u16* __restrict__ coll) {
    int idx = blockIdx.x * 256 + threadIdx.x;
    int bn = idx >> 8, e = idx & 255;
    float v = node_rand[bn] * Wnode[e] + bnode[e];
    rowb[idx] = v;
    colb[idx] = v;
    u16 h, l;
    bsplit(v, h, l);
    rowh[idx] = h; rowl[idx] = l;
    colh[idx] = h; coll[idx] = l;
}

// 32x32 tile transpose of data[b] -> dataT[b]; grid (8,8,BB), 256 thr
__global__ __launch_bounds__(256) void k_dataT(const float* __restrict__ data,
                                               float* __restrict__ dataT) {
    __shared__ float tile[32][33];
    int b = blockIdx.z;
    int r0 = blockIdx.y * 32, c0 = blockIdx.x * 32;
    int tx = threadIdx.x & 31, ty = threadIdx.x >> 5;
    const float* src = data + (size_t)b * NN * NN;
    float* dst = dataT + (size_t)b * NN * NN;
    #pragma unroll
    for (int i = 0; i < 4; i++)
        tile[ty + 8 * i][tx] = src[(size_t)(r0 + ty + 8 * i) * NN + c0 + tx];
    __syncthreads();
    #pragma unroll
    for (int i = 0; i < 4; i++)
        dst[(size_t)(c0 + ty + 8 * i) * NN + r0 + tx] = tile[tx][ty + 8 * i];
}

// ---------------- weight prep (all matrices, one dispatch): fp32 [K][N] -> bf16 hi/lo packed [kslab][n][32]
// grid 2560 blocks, 256 thr
__global__ __launch_bounds__(256) void k_wprep_all(
    const float* __restrict__ Wq, const float* __restrict__ Wk, const float* __restrict__ Wv,
    const float* __restrict__ Wc, const float* __restrict__ W1, const float* __restrict__ W2,
    u16* qh, u16* ql, u16* kh, u16* kl_, u16* vh, u16* vl,
    u16* ch, u16* cl, u16* f1h, u16* f1l, u16* f2h, u16* f2l) {
    int id = blockIdx.x;
    const float* W; u16 *Dh, *Dl; int K, N, mat, s, nt;
    if (id < 1280) {
        int seg = id / 320, local = id % 320;
        mat = local >> 5; int rem = local & 31; s = rem >> 2; nt = rem & 3;
        K = 256; N = 256;
        W  = seg == 0 ? Wq : seg == 1 ? Wk : seg == 2 ? Wv : Wc;
        Dh = seg == 0 ? qh : seg == 1 ? kh : seg == 2 ? vh : ch;
        Dl = seg == 0 ? ql : seg == 1 ? kl_ : seg == 2 ? vl : cl;
    } else if (id < 1920) {
        int local = id - 1280;
        mat = local >> 6; int rem = local & 63; s = rem >> 3; nt = rem & 7;
        K = 256; N = 512; W = W1; Dh = f1h; Dl = f1l;
    } else {
        int local = id - 1920;
        mat = local >> 6; int rem = local & 63; s = rem >> 2; nt = rem & 3;
        K = 512; N = 256; W = W2; Dh = f2h; Dl = f2l;
    }
    __shared__ u16 th[64][40], tl[64][40];
    int t = threadIdx.x;
    int kk = t >> 3, nl = (t & 7) * 8;
    const float* p = W + (size_t)mat * K * N + (size_t)(s * 32 + kk) * N + nt * 64 + nl;
    float4 f0 = *(const float4*)p;
    float4 f1v = *(const float4*)(p + 4);
    float fv[8] = {f0.x, f0.y, f0.z, f0.w, f1v.x, f1v.y, f1v.z, f1v.w};
    #pragma unroll
    for (int i = 0; i < 8; i++) bsplit(fv[i], th[nl + i][kk], tl[nl + i][kk]);
    __syncthreads();
    int n = t >> 2, ko = (t & 3) * 8;
    size_t dbase = (size_t)mat * K * N + (size_t)s * N * 32 + (size_t)nt * 64 * 32
                 + (size_t)n * 32 + ko;
    *(us8*)(Dh + dbase) = *(const us8*)&th[n][ko];
    *(us8*)(Dl + dbase) = *(const us8*)&tl[n][ko];
}

// ---------------- MFMA GEMM (3x bf16 split ~= fp32) ----------------
// A bf16 hi/lo plain rows [1024][K]; B bf16 hi/lo packed [kslab][n][32].
// block 256 thr = 4 waves; tile 64x64; wave -> 32x32 (2x2 16x16x32 MFMA).
__device__ __forceinline__ void mfma_gemm(const u16* __restrict__ Ah, const u16* __restrict__ Al,
                                          const u16* __restrict__ Bh, const u16* __restrict__ Bl,
                                          const float* __restrict__ bias, const float* __restrict__ R,
                                          float* __restrict__ Cf, u16* __restrict__ Ch,
                                          u16* __restrict__ Cl, int K, int Ncols, int relu) {
    __shared__ u16 AsH[64][40], AsL[64][40], BsH[64][40], BsL[64][40];
    int t = threadIdx.x;
    int lane = t & 63, wave = t >> 6;
    int quad = lane >> 4, l16 = lane & 15;
    int wy = wave >> 1, wx = wave & 1;
    int mBase = blockIdx.x * 64, nBase = blockIdx.y * 64;
    f32x4 acc00 = {0.f, 0.f, 0.f, 0.f}, acc01 = acc00, acc10 = acc00, acc11 = acc00;
    int ar = t >> 2, aks = (t & 3) * 8;
    const int nslab = K >> 5;
    const u16* apH = Ah + (size_t)(mBase + ar) * K + aks;
    const u16* apL = Al + (size_t)(mBase + ar) * K + aks;
    us8 rah = *(const us8*)apH;
    us8 ral = *(const us8*)apL;
    us8 rbh = *(const us8*)(Bh + (size_t)nBase * 32 + t * 8);
    us8 rbl = *(const us8*)(Bl + (size_t)nBase * 32 + t * 8);
    for (int s = 0; s < nslab; s++) {
        __syncthreads();
        *(us8*)&AsH[ar][aks] = rah;
        *(us8*)&AsL[ar][aks] = ral;
        *(us8*)&BsH[ar][aks] = rbh;
        *(us8*)&BsL[ar][aks] = rbl;
        __syncthreads();
        if (s + 1 < nslab) {
            rah = *(const us8*)(apH + (s + 1) * 32);
            ral = *(const us8*)(apL + (s + 1) * 32);
            rbh = *(const us8*)(Bh + ((size_t)(s + 1) * Ncols + nBase) * 32 + t * 8);
            rbl = *(const us8*)(Bl + ((size_t)(s + 1) * Ncols + nBase) * 32 + t * 8);
        }
        bfrag a_h0 = *(const bfrag*)&AsH[wy * 32 + l16][quad * 8];
        bfrag a_h1 = *(const bfrag*)&AsH[wy * 32 + 16 + l16][quad * 8];
        bfrag a_l0 = *(const bfrag*)&AsL[wy * 32 + l16][quad * 8];
        bfrag a_l1 = *(const bfrag*)&AsL[wy * 32 + 16 + l16][quad * 8];
        bfrag b_h0 = *(const bfrag*)&BsH[wx * 32 + l16][quad * 8];
        bfrag b_h1 = *(const bfrag*)&BsH[wx * 32 + 16 + l16][quad * 8];
        bfrag b_l0 = *(const bfrag*)&BsL[wx * 32 + l16][quad * 8];
        bfrag b_l1 = *(const bfrag*)&BsL[wx * 32 + 16 + l16][quad * 8];
        acc00 = __builtin_amdgcn_mfma_f32_16x16x32_bf16(a_h0, b_h0, acc00, 0, 0, 0);
        acc01 = __builtin_amdgcn_mfma_f32_16x16x32_bf16(a_h0, b_h1, acc01, 0, 0, 0);
        acc10 = __builtin_amdgcn_mfma_f32_16x16x32_bf16(a_h1, b_h0, acc10, 0, 0, 0);
        acc11 = __builtin_amdgcn_mfma_f32_16x16x32_bf16(a_h1, b_h1, acc11, 0, 0, 0);
        acc00 = __builtin_amdgcn_mfma_f32_16x16x32_bf16(a_h0, b_l0, acc00, 0, 0, 0);
        acc01 = __builtin_amdgcn_mfma_f32_16x16x32_bf16(a_h0, b_l1, acc01, 0, 0, 0);
        acc10 = __builtin_amdgcn_mfma_f32_16x16x32_bf16(a_h1, b_l0, acc10, 0, 0, 0);
        acc11 = __builtin_amdgcn_mfma_f32_16x16x32_bf16(a_h1, b_l1, acc11, 0, 0, 0);
        acc00 = __builtin_amdgcn_mfma_f32_16x16x32_bf16(a_l0, b_h0, acc00, 0, 0, 0);
        acc01 = __builtin_amdgcn_mfma_f32_16x16x32_bf16(a_l0, b_h1, acc01, 0, 0, 0);
        acc10 = __builtin_amdgcn_mfma_f32_16x16x32_bf16(a_l1, b_h0, acc10, 0, 0, 0);
        acc11 = __builtin_amdgcn_mfma_f32_16x16x32_bf16(a_l1, b_h1, acc11, 0, 0, 0);
    }
    int col0 = nBase + wx * 32 + l16;
    int col1 = col0 + 16;
    float bia0 = bias ? bias[col0] : 0.f;
    float bia1 = bias ? bias[col1] : 0.f;
    #pragma unroll
    for (int r = 0; r < 4; r++) {
        int row0 = mBase + wy * 32 + quad * 4 + r;
        int row1 = row0 + 16;
        float v00 = acc00[r] + bia0, v01 = acc01[r] + bia1;
        float v10 = acc10[r] + bia0, v11 = acc11[r] + bia1;
        if (R) {
            v00 += R[(size_t)row0 * Ncols + col0];
            v01 += R[(size_t)row0 * Ncols + col1];
            v10 += R[(size_t)row1 * Ncols + col0];
            v11 += R[(size_t)row1 * Ncols + col1];
        }
        if (relu) {
            v00 = fmaxf(v00, 0.f); v01 = fmaxf(v01, 0.f);
            v10 = fmaxf(v10, 0.f); v11 = fmaxf(v11, 0.f);
        }
        if (Cf) {
            Cf[(size_t)row0 * Ncols + col0] = v00;
            Cf[(size_t)row0 * Ncols + col1] = v01;
            Cf[(size_t)row1 * Ncols + col0] = v10;
            Cf[(size_t)row1 * Ncols + col1] = v11;
        } else {
            u16 h, l;
            bsplit(v00, h, l); Ch[(size_t)row0 * Ncols + col0] = h; Cl[(size_t)row0 * Ncols + col0] = l;
            bsplit(v01, h, l); Ch[(size_t)row0 * Ncols + col1] = h; Cl[(size_t)row0 * Ncols + col1] = l;
            bsplit(v10, h, l); Ch[(size_t)row1 * Ncols + col0] = h; Cl[(size_t)row1 * Ncols + col0] = l;
            bsplit(v11, h, l); Ch[(size_t)row1 * Ncols + col1] = h; Cl[(size_t)row1 * Ncols + col1] = l;
        }
    }
}

// z = j*3 + which(q/k/v); grid (16,4,6)
__global__ __launch_bounds__(256) void k_qkv(const u16* __restrict__ rowh, const u16* __restrict__ rowl,
                                             const u16* __restrict__ colh, const u16* __restrict__ coll,
                                             const u16* __restrict__ WqTh, const u16* __restrict__ WqTl,
                                             const u16* __restrict__ WkTh, const u16* __restrict__ WkTl,
                                             const u16* __restrict__ WvTh, const u16* __restrict__ WvTl,
                                             int lbase2,
                                             float* q0, float* k0, float* v0,
                                             float* q1, float* k1, float* v1) {
    int z = blockIdx.z;
    int j = z / 3, w = z % 3;
    const u16* Ah = (w == 0) ? (j ? colh : rowh) : (j ? rowh : colh);
    const u16* Al = (w == 0) ? (j ? coll : rowl) : (j ? rowl : coll);
    const u16* Wh = (w == 0 ? WqTh : (w == 1 ? WkTh : WvTh)) + (size_t)(lbase2 + j) * E * E;
    const u16* Wl = (w == 0 ? WqTl : (w == 1 ? WkTl : WvTl)) + (size_t)(lbase2 + j) * E * E;
    float* outs[6] = {q0, k0, v0, q1, k1, v1};
    mfma_gemm(Ah, Al, Wh, Wl, nullptr, nullptr, outs[z], nullptr, nullptr, E, E, 0);
}

__global__ __launch_bounds__(256) void k_mgemm(const u16* Ah0, const u16* Al0,
                                               const u16* Ah1, const u16* Al1,
                                               const u16* __restrict__ Bh, const u16* __restrict__ Bl,
                                               int lbase2, long wstride,
                                               const float* __restrict__ biasl, int bstride,
                                               const float* R0, const float* R1,
                                               float* Cf0, float* Cf1,
                                               u16* Ch0, u16* Cl0, u16* Ch1, u16* Cl1,
                                               int K, int Ncols, int relu) {
    int j = blockIdx.z;
    mfma_gemm(j ? Ah1 : Ah0, j ? Al1 : Al0,
              Bh + (size_t)(lbase2 + j) * wstride, Bl + (size_t)(lbase2 + j) * wstride,
              biasl ? biasl + (size_t)j * bstride : nullptr,
              R0 ? (j ? R1 : R0) : nullptr,
              Cf0 ? (j ? Cf1 : Cf0) : nullptr,
              Ch0 ? (j ? Ch1 : Ch0) : nullptr,
              Cl0 ? (j ? Cl1 : Cl0) : nullptr,
              K, Ncols, relu);
}

// ---------------- fused attention ----------------
// grid (B*H=64, 8 n-groups of 32, 2 j), 256 thr; 8 lanes per row; out bf16 hi/lo.
__global__ __launch_bounds__(256) void k_attn(const float* __restrict__ q0, const float* __restrict__ k0,
                                              const float* __restrict__ v0, const float* __restrict__ q1,
                                              const float* __restrict__ k1, const float* __restrict__ v1,
                                              const float* __restrict__ data, const float* __restrict__ dataT,
                                              const float* __restrict__ stats,
                                              const float* __restrict__ c1c0, int lj_base,
                                              u16* __restrict__ atth0, u16* __restrict__ attl0,
                                              u16* __restrict__ atth1, u16* __restrict__ attl1) {
    int bh = blockIdx.x;
    int b = bh >> 4, h = bh & 15;
    int ng = blockIdx.y;
    int j = blockIdx.z;
    const float* q = j ? q1 : q0;
    const float* k = j ? k1 : k0;
    const float* v = j ? v1 : v0;
    float mn = stats[b], inv = stats[4 + b];
    float c1 = c1c0[(lj_base + j) * 16 + h];
    float c0 = c1c0[160 + (lj_base + j) * 16 + h];
    float c1p = inv * c1;
    float c0p = c0 - mn * c1p;

    __shared__ float kl[256][20];
    __shared__ float vl[256][20];
    int t = threadIdx.x;
    {
        int c = t & 3, mb = t >> 2;
        #pragma unroll
        for (int it = 0; it < 4; it++) {
            int m = mb + 64 * it;
            const float* kp = k + ((size_t)(b * NN + m) * E) + h * DD + c * 4;
            const float* vp = v + ((size_t)(b * NN + m) * E) + h * DD + c * 4;
            *(float4*)&kl[m][c * 4] = *(const float4*)kp;
            *(float4*)&vl[m][c * 4] = *(const float4*)vp;
        }
    }
    __syncthreads();

    int lane = t & 63, w = t >> 6;
    int r = lane >> 3, ml = lane & 7;
    int n = ng * 32 + w * 8 + r;

    float qr[16];
    const float* qp = q + ((size_t)(b * NN + n) * E) + h * DD;
    #pragma unroll
    for (int d4 = 0; d4 < 4; d4++) {
        float4 q4 = *(const float4*)(qp + d4 * 4);
        qr[d4 * 4 + 0] = q4.x; qr[d4 * 4 + 1] = q4.y;
        qr[d4 * 4 + 2] = q4.z; qr[d4 * 4 + 3] = q4.w;
    }
    const float* pedge = (j ? dataT : data) + (size_t)b * NN * NN + (size_t)n * NN;

    float sum = 0.f;
    float acc[16] = {};
    for (int i = 0; i < 32; i++) {
        int m = ml + 8 * i;
        float4 ka = *(const float4*)&kl[m][0];
        float4 kb = *(const float4*)&kl[m][4];
        float4 kc = *(const float4*)&kl[m][8];
        float4 kd = *(const float4*)&kl[m][12];
        float s0 = qr[0] * ka.x + qr[1] * ka.y + qr[2] * ka.z + qr[3] * ka.w;
        float s1 = qr[4] * kb.x + qr[5] * kb.y + qr[6] * kb.z + qr[7] * kb.w;
        float s2 = qr[8] * kc.x + qr[9] * kc.y + qr[10] * kc.z + qr[11] * kc.w;
        float s3 = qr[12] * kd.x + qr[13] * kd.y + qr[14] * kd.z + qr[15] * kd.w;
        float s = ((s0 + s1) + (s2 + s3)) * 0.25f + pedge[m] * c1p + c0p;
        float e = __expf(s);
        sum += e;
        float4 va = *(const float4*)&vl[m][0];
        float4 vb = *(const float4*)&vl[m][4];
        float4 vc = *(const float4*)&vl[m][8];
        float4 vd = *(const float4*)&vl[m][12];
        acc[0] += e * va.x;  acc[1] += e * va.y;  acc[2] += e * va.z;  acc[3] += e * va.w;
        acc[4] += e * vb.x;  acc[5] += e * vb.y;  acc[6] += e * vb.z;  acc[7] += e * vb.w;
        acc[8] += e * vc.x;  acc[9] += e * vc.y;  acc[10] += e * vc.z; acc[11] += e * vc.w;
        acc[12] += e * vd.x; acc[13] += e * vd.y; acc[14] += e * vd.z; acc[15] += e * vd.w;
    }
    #pragma unroll
    for (int mask = 1; mask <= 4; mask <<= 1) {
        sum += __shfl_xor(sum, mask);
        #pragma unroll
        for (int d = 0; d < 16; d++) acc[d] += __shfl_xor(acc[d], mask);
    }
    if (ml == 0) {
        float invs = 1.f / sum;
        u16 hh[16], ll[16];
        #pragma unroll
        for (int d = 0; d < 16; d++) bsplit(acc[d] * invs, hh[d], ll[d]);
        size_t base = ((size_t)(b * NN + n) * E) + h * DD;
        u16* oh = (j ? atth1 : atth0) + base;
        u16* ol = (j ? attl1 : attl0) + base;
        *(us8*)oh = *(const us8*)&hh[0];
        *(us8*)(oh + 8) = *(const us8*)&hh[8];
        *(us8*)ol = *(const us8*)&ll[0];
        *(us8*)(ol + 8) = *(const us8*)&ll[8];
    }
}

// ---------------- instance norm over node dim ----------------
// grid (B, 2 j, 32 e-chunks of 8), 256 thr; fp32 + bf16 hi/lo outputs.
__global__ __launch_bounds__(256) void k_inorm(const float* __restrict__ Y0, const float* __restrict__ Y1,
                                               const float* __restrict__ wl, const float* __restrict__ bl,
                                               int pstride,
                                               float* Of0, float* Of1,
                                               u16* Oh0, u16* Ol0, u16* Oh1, u16* Ol1,
                                               float* __restrict__ fout) {
    int b = blockIdx.x, j = blockIdx.y;
    int ec = blockIdx.z * 8;
    const float* Y = (j ? Y1 : Y0) + (size_t)b * NN * E;
    float* O = (j ? Of1 : Of0) + (size_t)b * NN * E;
    u16* Oh = (j ? Oh1 : Oh0) + (size_t)b * NN * E;
    u16* Ol = (j ? Ol1 : Ol0) + (size_t)b * NN * E;
    const float* w = wl + (size_t)j * pstride;
    const float* bb = bl + (size_t)j * pstride;
    int t = threadIdx.x;
    int et = t & 7, n0 = t >> 3;
    int e = ec + et;
    float vals[8];
    float s = 0.f, s2 = 0.f;
    #pragma unroll
    for (int kk = 0; kk < 8; kk++) {
        float v = Y[(size_t)(n0 + 32 * kk) * E + e];
        vals[kk] = v;
        s += v;
        s2 += v * v;
    }
    __shared__ float ps[32][9], ps2[32][9];
    ps[n0][et] = s;
    ps2[n0][et] = s2;
    __syncthreads();
    float st = 0.f, st2 = 0.f;
    #pragma unroll
    for (int kk = 0; kk < 32; kk++) { st += ps[kk][et]; st2 += ps2[kk][et]; }
    float mu = st * (1.f / NN);
    float var = fmaxf(st2 * (1.f / NN) - mu * mu, 0.f);
    float scale = w[e] * rsqrtf(var + 1e-5f);
    float shift = bb[e] - mu * scale;
    #pragma unroll
    for (int kk = 0; kk < 8; kk++) {
        float vv = vals[kk] * scale + shift;
        size_t idx = (size_t)(n0 + 32 * kk) * E + e;
        O[idx] = vv;
        u16 hh, ll;
        bsplit(vv, hh, ll);
        Oh[idx] = hh;
        Ol[idx] = ll;
        if (fout) fout[(size_t)j * (BB * NN * E) + (size_t)b * NN * E + idx] = vv;
    }
}

// ---------------- host ----------------

extern "C" void kernel_launch(void* const* d_in, const int* in_sizes, int n_in,
                              void* d_out, int out_size, void* d_ws, size_t ws_size,
                              hipStream_t stream) {
    const float* data      = (const float*)d_in[0];
    const float* node_rand = (const float*)d_in[1];
    const float* Wnode     = (const float*)d_in[2];
    const float* bnode     = (const float*)d_in[3];
    const float* Wedge     = (const float*)d_in[4];
    const float* bedge     = (const float*)d_in[5];
    const float* Wq        = (const float*)d_in[6];
    const float* Wk        = (const float*)d_in[7];
    const float* Wv        = (const float*)d_in[8];
    const float* Wcomb     = (const float*)d_in[9];
    const float* bcomb     = (const float*)d_in[10];
    const float* n1w       = (const float*)d_in[11];
    const float* n1b       = (const float*)d_in[12];
    const float* W1        = (const float*)d_in[13];
    const float* b1        = (const float*)d_in[14];
    const float* W2        = (const float*)d_in[15];
    const float* b2        = (const float*)d_in[16];
    const float* n2w       = (const float*)d_in[17];
    const float* n2b       = (const float*)d_in[18];
    const float* Wmix      = (const float*)d_in[19];
    float* out = (float*)d_out;  // (row, col) concat

    float* ws = (float*)d_ws;
    const size_t T = (size_t)MROWS * E;      // 262144
    const size_t TF = (size_t)MROWS * FFH;   // 524288
    float* dataT = ws + 0 * T;
    float* row   = ws + 1 * T;
    float* col   = ws + 2 * T;
    float* q0    = ws + 3 * T;
    float* q1    = ws + 4 * T;
    float* k0    = ws + 5 * T;
    float* k1    = ws + 6 * T;
    float* v0    = ws + 7 * T;
    float* v1    = ws + 8 * T;
    float* stats = ws + 9 * T;
    float* pmin  = stats + 8;
    float* pmax  = pmin + 64;
    float* c1c0  = pmax + 64;
    u16* us = (u16*)(ws + 9 * T + 512);
    auto nxt = [&](size_t n) { u16* p = us; us += n; return p; };
    u16* rowh = nxt(T);  u16* rowl = nxt(T);
    u16* colh = nxt(T);  u16* coll = nxt(T);
    u16* atth0 = nxt(T); u16* attl0 = nxt(T);
    u16* atth1 = nxt(T); u16* attl1 = nxt(T);
    u16* o1h0 = nxt(T);  u16* o1l0 = nxt(T);
    u16* o1h1 = nxt(T);  u16* o1l1 = nxt(T);
    u16* ffhh0 = nxt(TF); u16* ffhl0 = nxt(TF);
    u16* ffhh1 = nxt(TF); u16* ffhl1 = nxt(TF);
    const size_t EE10 = (size_t)10 * E * E;
    const size_t EF10 = (size_t)10 * E * FFH;
    u16* WqTh = nxt(EE10); u16* WqTl = nxt(EE10);
    u16* WkTh = nxt(EE10); u16* WkTl = nxt(EE10);
    u16* WvTh = nxt(EE10); u16* WvTl = nxt(EE10);
    u16* WcTh = nxt(EE10); u16* WcTl = nxt(EE10);
    u16* W1Th = nxt(EF10); u16* W1Tl = nxt(EF10);
    u16* W2Th = nxt(EF10); u16* W2Tl = nxt(EF10);
    // fp32 aliases (liveness-checked)
    float* y0 = q0;   float* y1 = q1;     // comb out (q dead after attn)
    float* o1f0 = k0; float* o1f1 = k1;   // IN1 fp32 out (k dead after attn)
    float* y20 = q0;  float* y21 = q1;    // FF2 out (y dead after IN1)

    k_minmax1<<<dim3(BB, 16), 256, 0, stream>>>(data, pmin, pmax);
    k_final<<<1, 256, 0, stream>>>(pmin, pmax, Wedge, bedge, Wmix, stats, c1c0);
    k_emb<<<(BB * NN * E) / 256, 256, 0, stream>>>(node_rand, Wnode, bnode, row, col,
                                                   rowh, rowl, colh, coll);
    k_dataT<<<dim3(8, 8, BB), 256, 0, stream>>>(data, dataT);
    k_wprep_all<<<2560, 256, 0, stream>>>(Wq, Wk, Wv, Wcomb, W1, W2,
                                          WqTh, WqTl, WkTh, WkTl, WvTh, WvTl,
                                          WcTh, WcTl, W1Th, W1Tl, W2Th, W2Tl);

    for (int l = 0; l < LAYERS; l++) {
        k_qkv<<<dim3(16, 4, 6), 256, 0, stream>>>(rowh, rowl, colh, coll,
                                                  WqTh, WqTl, WkTh, WkTl, WvTh, WvTl, l * 2,
                                                  q0, k0, v0, q1, k1, v1);
        k_attn<<<dim3(64, 8, 2), 256, 0, stream>>>(q0, k0, v0, q1, k1, v1, data, dataT,
                                                   stats, c1c0, l * 2,
                                                   atth0, attl0, atth1, attl1);
        k_mgemm<<<dim3(16, 4, 2), 256, 0, stream>>>(atth0, attl0, atth1, attl1,
                                                    WcTh, WcTl, l * 2, (long)E * E,
                                                    bcomb + (size_t)l * 2 * E, E,
                                                    row, col, y0, y1,
                                                    nullptr, nullptr, nullptr, nullptr,
                                                    E, E, 0);
        k_inorm<<<dim3(BB, 2, 32), 256, 0, stream>>>(y0, y1,
                                                     n1w + (size_t)l * 2 * E, n1b + (size_t)l * 2 * E, E,
                                                     o1f0, o1f1, o1h0, o1l0, o1h1, o1l1, nullptr);
        k_mgemm<<<dim3(16, 8, 2), 256, 0, stream>>>(o1h0, o1l0, o1h1, o1l1,
                                                    W1Th, W1Tl, l * 2, (long)E * FFH,
                                                    b1 + (size_t)l * 2 * FFH, FFH,
                                                    nullptr, nullptr, nullptr, nullptr,
                                                    ffhh0, ffhl0, ffhh1, ffhl1,
                                                    E, FFH, 1);
        k_mgemm<<<dim3(16, 4, 2), 256, 0, stream>>>(ffhh0, ffhl0, ffhh1, ffhl1,
                                                    W2Th, W2Tl, l * 2, (long)FFH * E,
                                                    b2 + (size_t)l * 2 * E, E,
                                                    o1f0, o1f1, y20, y21,
                                                    nullptr, nullptr, nullptr, nullptr,
                                                    FFH, E, 0);
        k_inorm<<<dim3(BB, 2, 32), 256, 0, stream>>>(y20, y21,
                                                     n2w + (size_t)l * 2 * E, n2b + (size_t)l * 2 * E, E,
                                                     row, col, rowh, rowl, colh, coll,
                                                     (l == LAYERS - 1) ? out : nullptr);
    }
}